// Round 10
// baseline (434.758 us; speedup 1.0000x reference)
//
#include <hip/hip_runtime.h>
#include <math.h>

#define B_      2
#define N_      4096
#define H_      1024
#define HEADS_  16
#define DH_     64
#define M_      256
#define NSPLIT  8

constexpr float NORMALIZER = 0.35355339059327373f; // 64^-0.25
constexpr float RATIO      = 0.0625f;              // 256^-0.5
constexpr float KEPS       = 1e-3f;

typedef __bf16 bf16x8 __attribute__((ext_vector_type(8)));
typedef __bf16 bf16x4 __attribute__((ext_vector_type(4)));
typedef float  f32x4  __attribute__((ext_vector_type(4)));

// ======================================================================
// Split fp32 -> bf16 (hi, lo)
// ======================================================================
__global__ __launch_bounds__(256) void split_bf16(
    const float* __restrict__ src, __bf16* __restrict__ hi, __bf16* __restrict__ lo)
{
    int i = blockIdx.x * 256 + threadIdx.x;
    float4 v = ((const float4*)src)[i];
    float vv[4] = {v.x, v.y, v.z, v.w};
    bf16x4 h, l;
#pragma unroll
    for (int j = 0; j < 4; ++j) {
        __bf16 hh = (__bf16)vv[j];
        h[j] = hh;
        l[j] = (__bf16)(vv[j] - (float)hh);
    }
    ((bf16x4*)hi)[i] = h;
    ((bf16x4*)lo)[i] = l;
}

__global__ __launch_bounds__(256) void split_w(
    const float* __restrict__ W0, const float* __restrict__ W1,
    const float* __restrict__ W2, const float* __restrict__ W3,
    __bf16* __restrict__ hi, __bf16* __restrict__ lo)
{
    const float* src = W0;
    if (blockIdx.y == 1) src = W1;
    else if (blockIdx.y == 2) src = W2;
    else if (blockIdx.y == 3) src = W3;
    int i = blockIdx.x * 256 + threadIdx.x;
    size_t o = (size_t)blockIdx.y * 262144 + i;
    float4 v = ((const float4*)src)[i];
    float vv[4] = {v.x, v.y, v.z, v.w};
    bf16x4 h, l;
#pragma unroll
    for (int j = 0; j < 4; ++j) {
        __bf16 hh = (__bf16)vv[j];
        h[j] = hh;
        l[j] = (__bf16)(vv[j] - (float)hh);
    }
    ((bf16x4*)hi)[o] = h;
    ((bf16x4*)lo)[o] = l;
}

// ======================================================================
// MERGED QKV GEMM with ROLE-STAGGERED 3-PHASE schedule (round-9 verified:
// 138.5 us, MfmaUtil 50.9). UNCHANGED this round.
// ======================================================================
__global__ __launch_bounds__(512, 2) void gemm_qkv(
    const __bf16* __restrict__ Ah, const __bf16* __restrict__ Al,
    const __bf16* __restrict__ WH, const __bf16* __restrict__ WL,   // [3][H*H] packed Q,K,V
    const float* __restrict__ bq, const float* __restrict__ bk, const float* __restrict__ bv,
    __bf16* __restrict__ Qh, __bf16* __restrict__ Ql,
    __bf16* __restrict__ Kh, __bf16* __restrict__ Kl,
    __bf16* __restrict__ Vh, __bf16* __restrict__ Vl)
{
    __shared__ alignas(16) __bf16 lds[2][8][128 * 32];

    const int t    = threadIdx.x;
    const int lane = t & 63;
    const int lm   = lane & 15;
    const int lq   = lane >> 4;
    const int w    = t >> 6;
    const int wm   = (w >> 2) * 64;    // m half
    const int wn   = (w & 3) * 32;     // n quarter

    const int wg = blockIdx.x + 8 * blockIdx.y;
    const int sw = (wg & 7) * 64 + (wg >> 3);
    const int n0 = (sw & 7) * 128;
    const int m0 = (sw >> 3) * 128;
    const int K  = 1024;
    const int NK = 32;
    const size_t WSZ = (size_t)H_ * H_;

    const __bf16* mysrc;
    if      (w == 0) mysrc = Ah;
    else if (w == 1) mysrc = Al;
    else             mysrc = ((w & 1) ? WL : WH) + (size_t)((w - 2) >> 1) * WSZ;
    const int rbase  = (w < 2) ? m0 : n0;
    const int rsub   = lane >> 2;
    const int slot   = lane & 3;
    const int schunk = slot ^ ((lane >> 3) & 3);
    const __bf16* gbase = mysrc + (size_t)(rbase + rsub) * K + schunk * 8;

    f32x4 acc[3][4][2];
#pragma unroll
    for (int s = 0; s < 3; ++s)
#pragma unroll
        for (int i = 0; i < 4; ++i)
#pragma unroll
            for (int j = 0; j < 2; ++j) acc[s][i][j] = (f32x4){0.f, 0.f, 0.f, 0.f};

    const int swz = (lq ^ ((lm >> 1) & 3)) * 8;

    auto stage = [&](int buf, int k0) {
#pragma unroll
        for (int c = 0; c < 8; ++c) {
            const __bf16* g = gbase + (size_t)c * 16 * K + k0;
            __builtin_amdgcn_global_load_lds(
                (const __attribute__((address_space(1))) void*)g,
                (__attribute__((address_space(3))) void*)&lds[buf][w][c * 512],
                16, 0, 0);
        }
    };

#define MFMA_S(S) \
    _Pragma("unroll") \
    for (int i = 0; i < 4; ++i) \
        _Pragma("unroll") \
        for (int j = 0; j < 2; ++j) { \
            acc[S][i][j] = __builtin_amdgcn_mfma_f32_16x16x32_bf16(ah[i], bh[j], acc[S][i][j], 0, 0, 0); \
            acc[S][i][j] = __builtin_amdgcn_mfma_f32_16x16x32_bf16(al[i], bh[j], acc[S][i][j], 0, 0, 0); \
            acc[S][i][j] = __builtin_amdgcn_mfma_f32_16x16x32_bf16(ah[i], bl[j], acc[S][i][j], 0, 0, 0); \
        }

    stage(0, 0);
    int p = 0;
#pragma unroll 1
    for (int kt = 0; kt < NK; ++kt) {
        const int nb  = p ^ 1;
        const int nk0 = (kt + 1) * 32;
        const bool more = (kt < NK - 1);
        bf16x8 ah[4], al[4], bh[2], bl[2];

        // ---- P1: A + Wq (owners 0-3) ----
        if (w < 4) asm volatile("s_waitcnt vmcnt(0)" ::: "memory");
        asm volatile("s_barrier" ::: "memory");
#pragma unroll
        for (int i = 0; i < 4; ++i) {
            int off = (wm + i * 16 + lm) * 32 + swz;
            ah[i] = *(const bf16x8*)&lds[p][0][off];
            al[i] = *(const bf16x8*)&lds[p][1][off];
        }
#pragma unroll
        for (int j = 0; j < 2; ++j) {
            int off = (wn + j * 16 + lm) * 32 + swz;
            bh[j] = *(const bf16x8*)&lds[p][2][off];
            bl[j] = *(const bf16x8*)&lds[p][3][off];
        }
        if (more && w < 4) stage(nb, nk0);
        asm volatile("s_waitcnt lgkmcnt(0)" ::: "memory");
        __builtin_amdgcn_sched_barrier(0);
        __builtin_amdgcn_s_setprio(1);
        MFMA_S(0)
        __builtin_amdgcn_s_setprio(0);

        // ---- P2: Wk (owners 4-5) ----
        if (w == 4 || w == 5) asm volatile("s_waitcnt vmcnt(0)" ::: "memory");
        asm volatile("s_barrier" ::: "memory");
#pragma unroll
        for (int j = 0; j < 2; ++j) {
            int off = (wn + j * 16 + lm) * 32 + swz;
            bh[j] = *(const bf16x8*)&lds[p][4][off];
            bl[j] = *(const bf16x8*)&lds[p][5][off];
        }
        if (more && (w == 4 || w == 5)) stage(nb, nk0);
        asm volatile("s_waitcnt lgkmcnt(0)" ::: "memory");
        __builtin_amdgcn_sched_barrier(0);
        __builtin_amdgcn_s_setprio(1);
        MFMA_S(1)
        __builtin_amdgcn_s_setprio(0);

        // ---- P3: Wv (owners 6-7) ----
        if (w >= 6) asm volatile("s_waitcnt vmcnt(0)" ::: "memory");
        asm volatile("s_barrier" ::: "memory");
#pragma unroll
        for (int j = 0; j < 2; ++j) {
            int off = (wn + j * 16 + lm) * 32 + swz;
            bh[j] = *(const bf16x8*)&lds[p][6][off];
            bl[j] = *(const bf16x8*)&lds[p][7][off];
        }
        if (more && w >= 6) stage(nb, nk0);
        asm volatile("s_waitcnt lgkmcnt(0)" ::: "memory");
        __builtin_amdgcn_sched_barrier(0);
        __builtin_amdgcn_s_setprio(1);
        MFMA_S(2)
        __builtin_amdgcn_s_setprio(0);

        p ^= 1;
    }
#undef MFMA_S

    const float* biases[3] = {bq, bk, bv};
    __bf16* Chs[3] = {Qh, Kh, Vh};
    __bf16* Cls[3] = {Ql, Kl, Vl};
#pragma unroll
    for (int s = 0; s < 3; ++s) {
        float bsr[2];
#pragma unroll
        for (int j = 0; j < 2; ++j) bsr[j] = biases[s][n0 + wn + j * 16 + lm];
#pragma unroll
        for (int i = 0; i < 4; ++i)
#pragma unroll
            for (int r = 0; r < 4; ++r) {
                int rowm = m0 + wm + i * 16 + lq * 4 + r;
#pragma unroll
                for (int j = 0; j < 2; ++j) {
                    int col = n0 + wn + j * 16 + lm;
                    float o = acc[s][i][j][r] + bsr[j];
                    __bf16 hh = (__bf16)o;
                    Chs[s][(size_t)rowm * 1024 + col] = hh;
                    Cls[s][(size_t)rowm * 1024 + col] = (__bf16)(o - (float)hh);
                }
            }
    }
}

// ======================================================================
// Final projection GEMM (round-2 verified schedule + T1). UNCHANGED.
// ======================================================================
__global__ __launch_bounds__(512, 4) void gemm_out(
    const __bf16* __restrict__ Ah, const __bf16* __restrict__ Al,
    const __bf16* __restrict__ Bh, const __bf16* __restrict__ Bl,
    const float* __restrict__ bias, float* __restrict__ C0)
{
    __shared__ alignas(16) __bf16 lds[2][4][128 * 32];

    const int t    = threadIdx.x;
    const int lane = t & 63;
    const int lm   = lane & 15;
    const int lq   = lane >> 4;
    const int w    = t >> 6;
    const int wm   = (w >> 2) * 64;
    const int wn   = (w & 3) * 32;

    const int wg = blockIdx.x + 8 * blockIdx.y;
    const int sw = (wg & 7) * 64 + (wg >> 3);
    const int n0 = (sw & 7) * 128;
    const int m0 = (sw >> 3) * 128;
    const int K  = 1024;
    const int NK = 32;

    const int tw = w >> 1;
    const int hw = w & 1;
    const __bf16* mysrc = (tw == 0) ? Ah : (tw == 1) ? Al : (tw == 2) ? Bh : Bl;
    const int     rbase = ((tw < 2) ? m0 : n0) + hw * 64;
    const int rsub   = lane >> 2;
    const int slot   = lane & 3;
    const int schunk = slot ^ ((lane >> 3) & 3);
    const __bf16* gbase = mysrc + (size_t)(rbase + rsub) * K + schunk * 8;

    f32x4 acc[4][2];
#pragma unroll
    for (int i = 0; i < 4; ++i)
#pragma unroll
        for (int j = 0; j < 2; ++j) acc[i][j] = (f32x4){0.f, 0.f, 0.f, 0.f};

    const int swz = (lq ^ ((lm >> 1) & 3)) * 8;

    auto stage = [&](int buf, int k0) {
#pragma unroll
        for (int c = 0; c < 4; ++c) {
            const __bf16* g = gbase + (size_t)c * 16 * K + k0;
            __builtin_amdgcn_global_load_lds(
                (const __attribute__((address_space(1))) void*)g,
                (__attribute__((address_space(3))) void*)&lds[buf][tw][(hw * 64 + c * 16) * 32],
                16, 0, 0);
        }
    };

    auto compute = [&](int p) {
        const __bf16* tAh = lds[p][0];
        const __bf16* tAl = lds[p][1];
        const __bf16* tBh = lds[p][2];
        const __bf16* tBl = lds[p][3];
        bf16x8 bh[2], bl[2];
#pragma unroll
        for (int j = 0; j < 2; ++j) {
            int off = (wn + j * 16 + lm) * 32 + swz;
            bh[j] = *(const bf16x8*)&tBh[off];
            bl[j] = *(const bf16x8*)&tBl[off];
        }
#pragma unroll
        for (int i = 0; i < 4; ++i) {
            int off = (wm + i * 16 + lm) * 32 + swz;
            bf16x8 ah = *(const bf16x8*)&tAh[off];
            bf16x8 al = *(const bf16x8*)&tAl[off];
#pragma unroll
            for (int j = 0; j < 2; ++j) {
                acc[i][j] = __builtin_amdgcn_mfma_f32_16x16x32_bf16(ah, bh[j], acc[i][j], 0, 0, 0);
                acc[i][j] = __builtin_amdgcn_mfma_f32_16x16x32_bf16(al, bh[j], acc[i][j], 0, 0, 0);
                acc[i][j] = __builtin_amdgcn_mfma_f32_16x16x32_bf16(ah, bl[j], acc[i][j], 0, 0, 0);
            }
        }
    };

    stage(0, 0);
    int p = 0;
#pragma unroll 1
    for (int kk = 0; kk < NK - 1; ++kk) {
        stage(p ^ 1, (kk + 1) * 32);
        asm volatile("s_waitcnt vmcnt(4)" ::: "memory");
        asm volatile("s_barrier" ::: "memory");
        compute(p);
        asm volatile("s_barrier" ::: "memory");
        p ^= 1;
    }
    asm volatile("s_waitcnt vmcnt(0)" ::: "memory");
    asm volatile("s_barrier" ::: "memory");
    compute(p);

    float bsr[2];
#pragma unroll
    for (int j = 0; j < 2; ++j) bsr[j] = bias[n0 + wn + j * 16 + lm];
#pragma unroll
    for (int i = 0; i < 4; ++i)
#pragma unroll
        for (int r = 0; r < 4; ++r) {
            int rowm = m0 + wm + i * 16 + lq * 4 + r;
#pragma unroll
            for (int j = 0; j < 2; ++j) {
                int col = n0 + wn + j * 16 + lm;
                C0[(size_t)rowm * 1024 + col] = acc[i][j][r] + bsr[j];
            }
        }
}

// ======================================================================
// diag_k from bf16 hi/lo K
// ======================================================================
__global__ __launch_bounds__(256) void diag_kernel(
    const __bf16* __restrict__ Kh, const __bf16* __restrict__ Kl,
    float* __restrict__ diag, float* __restrict__ partials)
{
    int gt = blockIdx.x * 256 + threadIdx.x;
    int r  = gt >> 2;
    int q  = gt & 3;
    const bf16x8* ph = (const bf16x8*)(Kh + (size_t)r * 64 + q * 16);
    const bf16x8* pl = (const bf16x8*)(Kl + (size_t)r * 64 + q * 16);
    float s = 0.f;
#pragma unroll
    for (int i = 0; i < 2; ++i) {
        bf16x8 vh = ph[i], vl = pl[i];
#pragma unroll
        for (int j = 0; j < 8; ++j) {
            float x = (float)vh[j] + (float)vl[j];
            s += x * x;
        }
    }
    s += __shfl_xor(s, 1);
    s += __shfl_xor(s, 2);
    float d = -0.5f * s;
    if (q == 0) {
        int h = r & 15, bn = r >> 4;
        int n = bn & 4095, b = bn >> 12;
        diag[(((size_t)b * 16 + h) << 12) + n] = d;
    }
    __shared__ float red[256];
    red[threadIdx.x] = d;
    __syncthreads();
    for (int s2 = 128; s2 > 0; s2 >>= 1) {
        if (threadIdx.x < s2) red[threadIdx.x] = fmaxf(red[threadIdx.x], red[threadIdx.x + s2]);
        __syncthreads();
    }
    if (threadIdx.x == 0) partials[blockIdx.x] = red[0];
}

__global__ __launch_bounds__(256) void reduce_stab(
    const float* __restrict__ partials, float* __restrict__ stab, int n)
{
    float m = -3.0e38f;
    for (int i = threadIdx.x; i < n; i += 256) m = fmaxf(m, partials[i]);
    __shared__ float red[256];
    red[threadIdx.x] = m;
    __syncthreads();
    for (int s2 = 128; s2 > 0; s2 >>= 1) {
        if (threadIdx.x < s2) red[threadIdx.x] = fmaxf(red[threadIdx.x], red[threadIdx.x + s2]);
        __syncthreads();
    }
    if (threadIdx.x == 0) stab[0] = red[0];
}

// ======================================================================
// ctx via MFMA. T14 prefetch for V/K/diag (rounds 6-8, verified).
// NEW: EPAD removed. k_cumsum computed exactly in fp32 registers
// (kcum[mf] += kf in the exp loop; 2x shfl_xor over lq completes the
// n-sum) -> PV drops ef 5->4 (-20% MFMA), vT shrinks to [64][72], the
// constant-rows init is gone. kcum partials to kcump[s][bh][m].
// ======================================================================
__global__ __launch_bounds__(256, 2) void ctx_mfma(
    const __bf16* __restrict__ Kh, const __bf16* __restrict__ Kl,
    const __bf16* __restrict__ Vh, const __bf16* __restrict__ Vl,
    const __bf16* __restrict__ projH, const __bf16* __restrict__ projL,
    const float* __restrict__ diag, const float* __restrict__ stabp,
    float* __restrict__ ctxp, float* __restrict__ kcump)
{
    __shared__ alignas(16) char ldsbuf[55296];
    __shared__ float dg[64];
    __bf16* kfTh = (__bf16*)ldsbuf;              // [128][72]
    __bf16* kfTl = kfTh + 9216;                  // [128][72]
    __bf16* vTh  = kfTl + 9216;                  // [64][72]
    __bf16* vTl  = vTh + 4608;                   // [64][72]
    float*  ctxe = (float*)ldsbuf;               // [128][65] epilogue alias (33280 B)

    const int t    = threadIdx.x;
    const int lane = t & 63;
    const int w    = t >> 6;
    const int lm   = lane & 15;
    const int lq   = lane >> 4;
    const int bh   = blockIdx.z;
    const int b    = bh >> 4, h = bh & 15;
    const int mh   = blockIdx.y;
    const int slice = blockIdx.x;
    const int mwave = mh * 128 + w * 32;
    const float stab = stabp[0];
    const size_t rowbase = (size_t)b * N_ * H_ + (size_t)h * DH_;
    const float* diag_bh = diag + (size_t)bh * N_;

    bf16x8 ph[2][2], pl[2][2];
#pragma unroll
    for (int mf = 0; mf < 2; ++mf)
#pragma unroll
        for (int ks = 0; ks < 2; ++ks) {
            size_t pa = (size_t)(mwave + mf * 16 + lm) * 64 + ks * 32 + lq * 8;
            ph[mf][ks] = *(const bf16x8*)(projH + pa);
            pl[mf][ks] = *(const bf16x8*)(projL + pa);
        }

    f32x4 acc[2][4];
#pragma unroll
    for (int mf = 0; mf < 2; ++mf)
#pragma unroll
        for (int ef = 0; ef < 4; ++ef) acc[mf][ef] = (f32x4){0.f, 0.f, 0.f, 0.f};
    float kcum[2] = {0.f, 0.f};

    const int nl = t >> 2, dc = (t & 3) * 16;
    bf16x8 v0, v1, u0, u1;
    bf16x8 kh_p[4][2], kl_p[4][2];
    float dgr = 0.f;
    {
        const int nbase = slice * (N_ / NSPLIT);
        size_t va = rowbase + (size_t)(nbase + nl) * H_ + dc;
        v0 = *(const bf16x8*)(Vh + va);
        v1 = *(const bf16x8*)(Vh + va + 8);
        u0 = *(const bf16x8*)(Vl + va);
        u1 = *(const bf16x8*)(Vl + va + 8);
#pragma unroll
        for (int nf = 0; nf < 4; ++nf)
#pragma unroll
            for (int ks = 0; ks < 2; ++ks) {
                size_t ka = rowbase + (size_t)(nbase + nf * 16 + lm) * H_ + ks * 32 + lq * 8;
                kh_p[nf][ks] = *(const bf16x8*)(Kh + ka);
                kl_p[nf][ks] = *(const bf16x8*)(Kl + ka);
            }
        if (t < 64) dgr = diag_bh[nbase + t];
    }

    for (int tile = 0; tile < 8; ++tile) {
        const int n0 = slice * (N_ / NSPLIT) + tile * 64;
        __syncthreads();   // barrier A

#pragma unroll
        for (int j = 0; j < 8; ++j) {
            vTh[(dc + j) * 72 + nl]     = v0[j];
            vTh[(dc + 8 + j) * 72 + nl] = v1[j];
            vTl[(dc + j) * 72 + nl]     = u0[j];
            vTl[(dc + 8 + j) * 72 + nl] = u1[j];
        }
        if (t < 64) dg[t] = dgr - stab;

        f32x4 dsh[4][2];
#pragma unroll
        for (int nf = 0; nf < 4; ++nf) {
#pragma unroll
            for (int mf = 0; mf < 2; ++mf) dsh[nf][mf] = (f32x4){0.f, 0.f, 0.f, 0.f};
#pragma unroll
            for (int mf = 0; mf < 2; ++mf)
#pragma unroll
                for (int ks = 0; ks < 2; ++ks) {
                    dsh[nf][mf] = __builtin_amdgcn_mfma_f32_16x16x32_bf16(kh_p[nf][ks], ph[mf][ks], dsh[nf][mf], 0, 0, 0);
                    dsh[nf][mf] = __builtin_amdgcn_mfma_f32_16x16x32_bf16(kl_p[nf][ks], ph[mf][ks], dsh[nf][mf], 0, 0, 0);
                    dsh[nf][mf] = __builtin_amdgcn_mfma_f32_16x16x32_bf16(kh_p[nf][ks], pl[mf][ks], dsh[nf][mf], 0, 0, 0);
                }
        }

        __syncthreads();   // barrier B

        if (tile < 7) {
            size_t va = rowbase + (size_t)(n0 + 64 + nl) * H_ + dc;
            v0 = *(const bf16x8*)(Vh + va);
            v1 = *(const bf16x8*)(Vh + va + 8);
            u0 = *(const bf16x8*)(Vl + va);
            u1 = *(const bf16x8*)(Vl + va + 8);
#pragma unroll
            for (int nf = 0; nf < 4; ++nf)
#pragma unroll
                for (int ks = 0; ks < 2; ++ks) {
                    size_t ka = rowbase + (size_t)(n0 + 64 + nf * 16 + lm) * H_ + ks * 32 + lq * 8;
                    kh_p[nf][ks] = *(const bf16x8*)(Kh + ka);
                    kl_p[nf][ks] = *(const bf16x8*)(Kl + ka);
                }
            if (t < 64) dgr = diag_bh[n0 + 64 + t];
        }

        // exp -> kf bf16 hi/lo -> kfT; fp32 kcum accumulates alongside
#pragma unroll
        for (int nf = 0; nf < 4; ++nf) {
            float4 dgv = *(const float4*)&dg[nf * 16 + lq * 4];
            float dga[4] = {dgv.x, dgv.y, dgv.z, dgv.w};
#pragma unroll
            for (int mf = 0; mf < 2; ++mf) {
                int mrow = w * 32 + mf * 16 + lm;
                bf16x4 vh_, vl_;
#pragma unroll
                for (int r = 0; r < 4; ++r) {
                    float kf = RATIO * (__expf(dga[r] + NORMALIZER * dsh[nf][mf][r]) + KEPS);
                    kcum[mf] += kf;
                    __bf16 hh = (__bf16)kf;
                    vh_[r] = hh;
                    vl_[r] = (__bf16)(kf - (float)hh);
                }
                int nbase = nf * 16 + lq * 4;
                *(bf16x4*)&kfTh[mrow * 72 + nbase] = vh_;
                *(bf16x4*)&kfTl[mrow * 72 + nbase] = vl_;
            }
        }

        // ctx accumulate: acc[mf][ef] += kfT[m][n] @ vT[e][n], e<64 only
#pragma unroll
        for (int ks = 0; ks < 2; ++ks) {
#pragma unroll
            for (int mf = 0; mf < 2; ++mf) {
                bf16x8 af = *(const bf16x8*)&kfTh[(w * 32 + mf * 16 + lm) * 72 + ks * 32 + lq * 8];
                bf16x8 afl = *(const bf16x8*)&kfTl[(w * 32 + mf * 16 + lm) * 72 + ks * 32 + lq * 8];
#pragma unroll
                for (int ef = 0; ef < 4; ++ef) {
                    bf16x8 bfh = *(const bf16x8*)&vTh[(ef * 16 + lm) * 72 + ks * 32 + lq * 8];
                    bf16x8 bfl = *(const bf16x8*)&vTl[(ef * 16 + lm) * 72 + ks * 32 + lq * 8];
                    acc[mf][ef] = __builtin_amdgcn_mfma_f32_16x16x32_bf16(af,  bfh, acc[mf][ef], 0, 0, 0);
                    acc[mf][ef] = __builtin_amdgcn_mfma_f32_16x16x32_bf16(afl, bfh, acc[mf][ef], 0, 0, 0);
                    acc[mf][ef] = __builtin_amdgcn_mfma_f32_16x16x32_bf16(af,  bfl, acc[mf][ef], 0, 0, 0);
                }
            }
        }
    }

    // kcum: complete the n-sum across the 4 lq lanes sharing lm
#pragma unroll
    for (int mf = 0; mf < 2; ++mf) {
        kcum[mf] += __shfl_xor(kcum[mf], 16);
        kcum[mf] += __shfl_xor(kcum[mf], 32);
    }
    if (lq == 0) {
#pragma unroll
        for (int mf = 0; mf < 2; ++mf)
            kcump[(size_t)slice * 8192 + (size_t)bh * 256 + mwave + mf * 16 + lm] = kcum[mf];
    }

    // epilogue: acc -> ctxe[m][e] (fp32, stride 65) -> global [s][bh][e][m]
    __syncthreads();
#pragma unroll
    for (int mf = 0; mf < 2; ++mf)
#pragma unroll
        for (int ef = 0; ef < 4; ++ef)
#pragma unroll
            for (int r = 0; r < 4; ++r) {
                int ml = w * 32 + mf * 16 + lq * 4 + r;
                int e  = ef * 16 + lm;
                ctxe[ml * 65 + e] = acc[mf][ef][r];
            }
    __syncthreads();
    const size_t SLICE = (size_t)(B_ * HEADS_) * 64 * M_;
    const size_t obase = (size_t)slice * SLICE + (size_t)bh * 64 * M_;
    for (int i = t; i < 64 * 128; i += 256) {
        int e = i >> 7, ml = i & 127;
        ctxp[obase + (size_t)e * M_ + mh * 128 + ml] = ctxe[ml * 65 + e];
    }
}

// ======================================================================
// Reduce ctx partials over slices -> bf16 hi/lo ctxT[bh][e][m] (e<64),
// plus kcum partials -> fp32 kcumT[bh][m] (blocks 2048..2079).
// ======================================================================
__global__ __launch_bounds__(256) void ctx_reduce(
    const float* __restrict__ ctxp, const float* __restrict__ kcump,
    __bf16* __restrict__ ctxTh, __bf16* __restrict__ ctxTl, float* __restrict__ kcumT)
{
    const int bid = blockIdx.x;
    if (bid < 2048) {
        int idx = bid * 256 + threadIdx.x;            // [0, 32*64*256)
        const size_t SLICE = (size_t)(B_ * HEADS_) * 64 * M_;
        float s = 0.f;
#pragma unroll
        for (int k = 0; k < NSPLIT; ++k) s += ctxp[(size_t)k * SLICE + idx];
        __bf16 hh = (__bf16)s;
        ctxTh[idx] = hh;
        ctxTl[idx] = (__bf16)(s - (float)hh);
    } else {
        int idx = (bid - 2048) * 256 + threadIdx.x;   // [0, 32*256)
        float s = 0.f;
#pragma unroll
        for (int k = 0; k < NSPLIT; ++k) s += kcump[(size_t)k * 8192 + idx];
        kcumT[idx] = s;
    }
}

// ======================================================================
// out via MFMA. grid (N/256, 32 bh), 512 thr / 8 waves. ctxT (64 rows,
// EPAD gone) staged in LDS w/ source XOR swizzle; proj reg-dbuffered
// (round 8). Denominator now an exact fp32 dot with kcumT inside the
// qf loop + 4x shfl_xor over lm — out-GEMM drops ef 5->4 (-20% MFMA),
// staging -20% bytes, LDS 152->120 KB.
// ======================================================================
__global__ __launch_bounds__(512, 2) void out_mfma(
    const __bf16* __restrict__ Qh, const __bf16* __restrict__ Ql,
    const __bf16* __restrict__ projH, const __bf16* __restrict__ projL,
    const __bf16* __restrict__ ctxTh, const __bf16* __restrict__ ctxTl,
    const float* __restrict__ kcumT,
    __bf16* __restrict__ attnH, __bf16* __restrict__ attnL)
{
    __shared__ alignas(16) __bf16 ctxLh[64 * 256];
    __shared__ alignas(16) __bf16 ctxLl[64 * 256];
    __shared__ alignas(16) __bf16 qfh[8][32][72];
    __shared__ alignas(16) __bf16 qfl[8][32][72];

    const int t    = threadIdx.x;
    const int lane = t & 63;
    const int w    = t >> 6;
    const int lm   = lane & 15;
    const int lq   = lane >> 4;
    const int bh   = blockIdx.y;
    const int b    = bh >> 4, h = bh & 15;
    const int nw   = blockIdx.x * 256 + w * 32;
    const size_t rowbase = (size_t)b * N_ * H_ + (size_t)h * DH_;

    const __bf16* cth = ctxTh + (size_t)bh * 64 * M_;
    const __bf16* ctl = ctxTl + (size_t)bh * 64 * M_;
    const float*  kct = kcumT + (size_t)bh * M_;

    {
        const int r_in = lane >> 5;
        const int cp   = lane & 31;
#pragma unroll
        for (int c = 0; c < 4; ++c) {
            int idx = w * 4 + c;                  // 1KiB chunk id 0..31
            int r   = idx * 2 + r_in;             // row 0..63
            int gc  = cp ^ (r & 7);
            const __bf16* gh = cth + (size_t)r * 256 + gc * 8;
            const __bf16* gl = ctl + (size_t)r * 256 + gc * 8;
            __builtin_amdgcn_global_load_lds(
                (const __attribute__((address_space(1))) void*)gh,
                (__attribute__((address_space(3))) void*)&ctxLh[idx * 512],
                16, 0, 0);
            __builtin_amdgcn_global_load_lds(
                (const __attribute__((address_space(1))) void*)gl,
                (__attribute__((address_space(3))) void*)&ctxLl[idx * 512],
                16, 0, 0);
        }
    }

    bf16x8 qh_[2][2], ql_[2][2];
#pragma unroll
    for (int nf = 0; nf < 2; ++nf)
#pragma unroll
        for (int ks = 0; ks < 2; ++ks) {
            size_t qa = rowbase + (size_t)(nw + nf * 16 + lm) * H_ + ks * 32 + lq * 8;
            qh_[nf][ks] = *(const bf16x8*)(Qh + qa);
            ql_[nf][ks] = *(const bf16x8*)(Ql + qa);
        }
    bf16x8 pc_h[4][2], pc_l[4][2];
#pragma unroll
    for (int mf = 0; mf < 4; ++mf)
#pragma unroll
        for (int ks = 0; ks < 2; ++ks) {
            size_t pa = (size_t)(mf * 16 + lm) * 64 + ks * 32 + lq * 8;
            pc_h[mf][ks] = *(const bf16x8*)(projH + pa);
            pc_l[mf][ks] = *(const bf16x8*)(projL + pa);
        }

    __syncthreads();

    f32x4 accO[2][4];
#pragma unroll
    for (int nf = 0; nf < 2; ++nf)
#pragma unroll
        for (int ef = 0; ef < 4; ++ef) accO[nf][ef] = (f32x4){0.f, 0.f, 0.f, 0.f};
    float den_p[2][4];
#pragma unroll
    for (int nf = 0; nf < 2; ++nf)
#pragma unroll
        for (int r = 0; r < 4; ++r) den_p[nf][r] = 0.f;

#pragma unroll
    for (int mc = 0; mc < 4; ++mc) {
        const int m0 = mc * 64;
        // kcum for this m-chunk (L3-hot, hides under dash)
        float kc[4];
#pragma unroll
        for (int mf = 0; mf < 4; ++mf) kc[mf] = kct[m0 + mf * 16 + lm];
        // dash from register-cached proj
        f32x4 dsh[2][4];
#pragma unroll
        for (int nf = 0; nf < 2; ++nf)
#pragma unroll
            for (int mf = 0; mf < 4; ++mf) dsh[nf][mf] = (f32x4){0.f, 0.f, 0.f, 0.f};
#pragma unroll
        for (int mf = 0; mf < 4; ++mf)
#pragma unroll
            for (int ks = 0; ks < 2; ++ks)
#pragma unroll
                for (int nf = 0; nf < 2; ++nf) {
                    dsh[nf][mf] = __builtin_amdgcn_mfma_f32_16x16x32_bf16(qh_[nf][ks], pc_h[mf][ks], dsh[nf][mf], 0, 0, 0);
                    dsh[nf][mf] = __builtin_amdgcn_mfma_f32_16x16x32_bf16(ql_[nf][ks], pc_h[mf][ks], dsh[nf][mf], 0, 0, 0);
                    dsh[nf][mf] = __builtin_amdgcn_mfma_f32_16x16x32_bf16(qh_[nf][ks], pc_l[mf][ks], dsh[nf][mf], 0, 0, 0);
                }
        bf16x8 pn_h[4][2], pn_l[4][2];
        if (mc < 3) {
#pragma unroll
            for (int mf = 0; mf < 4; ++mf)
#pragma unroll
                for (int ks = 0; ks < 2; ++ks) {
                    size_t pa = (size_t)((m0 + 64) + mf * 16 + lm) * 64 + ks * 32 + lq * 8;
                    pn_h[mf][ks] = *(const bf16x8*)(projH + pa);
                    pn_l[mf][ks] = *(const bf16x8*)(projL + pa);
                }
        }
        // exp -> qf bf16 hi/lo -> LDS; den accumulates in fp32
#pragma unroll
        for (int nf = 0; nf < 2; ++nf)
#pragma unroll
            for (int mf = 0; mf < 4; ++mf)
#pragma unroll
                for (int r = 0; r < 4; ++r) {
                    float qf = RATIO * (__expf(NORMALIZER * dsh[nf][mf][r]) + KEPS);
                    den_p[nf][r] += qf * kc[mf];
                    __bf16 hh = (__bf16)qf;
                    int nloc = nf * 16 + lq * 4 + r;
                    qfh[w][nloc][mf * 16 + lm] = hh;
                    qfl[w][nloc][mf * 16 + lm] = (__bf16)(qf - (float)hh);
                }
        // out GEMM from LDS-staged ctx (e<64)
#pragma unroll
        for (int ks = 0; ks < 2; ++ks) {
            bf16x8 af[2], afl[2];
#pragma unroll
            for (int nf = 0; nf < 2; ++nf) {
                af[nf]  = *(const bf16x8*)&qfh[w][nf * 16 + lm][ks * 32 + lq * 8];
                afl[nf] = *(const bf16x8*)&qfl[w][nf * 16 + lm][ks * 32 + lq * 8];
            }
#pragma unroll
            for (int ef = 0; ef < 4; ++ef) {
                int row = ef * 16 + lm;
                int sc  = ((m0 >> 3) + ks * 4 + lq) ^ (lm & 7);
                int off = row * 256 + sc * 8;
                bf16x8 bfh = *(const bf16x8*)&ctxLh[off];
                bf16x8 bfl = *(const bf16x8*)&ctxLl[off];
#pragma unroll
                for (int nf = 0; nf < 2; ++nf) {
                    accO[nf][ef] = __builtin_amdgcn_mfma_f32_16x16x32_bf16(af[nf],  bfh, accO[nf][ef], 0, 0, 0);
                    accO[nf][ef] = __builtin_amdgcn_mfma_f32_16x16x32_bf16(afl[nf], bfh, accO[nf][ef], 0, 0, 0);
                    accO[nf][ef] = __builtin_amdgcn_mfma_f32_16x16x32_bf16(af[nf],  bfl, accO[nf][ef], 0, 0, 0);
                }
            }
        }
        if (mc < 3) {
#pragma unroll
            for (int mf = 0; mf < 4; ++mf)
#pragma unroll
                for (int ks = 0; ks < 2; ++ks) {
                    pc_h[mf][ks] = pn_h[mf][ks];
                    pc_l[mf][ks] = pn_l[mf][ks];
                }
        }
    }

    // complete the m-sum of den across the 16 lm lanes (masks < 16 keep lq)
#pragma unroll
    for (int nf = 0; nf < 2; ++nf)
#pragma unroll
        for (int r = 0; r < 4; ++r) {
            float d = den_p[nf][r];
            d += __shfl_xor(d, 1);
            d += __shfl_xor(d, 2);
            d += __shfl_xor(d, 4);
            d += __shfl_xor(d, 8);
            den_p[nf][r] = 1.f / d;
        }

#pragma unroll
    for (int nf = 0; nf < 2; ++nf)
#pragma unroll
        for (int ef = 0; ef < 4; ++ef)
#pragma unroll
            for (int r = 0; r < 4; ++r) {
                float o = accO[nf][ef][r] * den_p[nf][r];
                __bf16 hh = (__bf16)o;
                size_t oa = rowbase + (size_t)(nw + nf * 16 + lq * 4 + r) * H_ + ef * 16 + lm;
                attnH[oa] = hh;
                attnL[oa] = (__bf16)(o - (float)hh);
            }
}

// ======================================================================
extern "C" void kernel_launch(void* const* d_in, const int* in_sizes, int n_in,
                              void* d_out, int out_size, void* d_ws, size_t ws_size,
                              hipStream_t stream) {
    const float* hs   = (const float*)d_in[0];
    const float* Wq   = (const float*)d_in[1];
    const float* bq   = (const float*)d_in[2];
    const float* Wk   = (const float*)d_in[3];
    const float* bk   = (const float*)d_in[4];
    const float* Wv   = (const float*)d_in[5];
    const float* bv   = (const float*)d_in[6];
    const float* Wo   = (const float*)d_in[7];
    const float* bo   = (const float*)d_in[8];
    const float* proj = (const float*)d_in[9];
    float* out = (float*)d_out;

    const size_t QSZ = (size_t)B_ * N_ * H_;             // 8388608
    const size_t WSZ = (size_t)H_ * H_;                  // 1048576
    const size_t CTXT = (size_t)B_ * HEADS_ * 64 * M_;   // 524288

    __bf16* Qh  = (__bf16*)d_ws;
    __bf16* Ql  = Qh + QSZ;
    __bf16* Kh  = Ql + QSZ;
    __bf16* Kl  = Kh + QSZ;
    __bf16* Vh  = Kl + QSZ;
    __bf16* Vl  = Vh + QSZ;
    __bf16* hsH = Vl + QSZ;      // aliased as attnH after hs consumed
    __bf16* hsL = hsH + QSZ;     // aliased as attnL
    __bf16* WH  = hsL + QSZ;
    __bf16* WL  = WH + 4 * WSZ;
    __bf16* projH = WL + 4 * WSZ;
    __bf16* projL = projH + (size_t)M_ * DH_;
    __bf16* ctxTh = projL + (size_t)M_ * DH_;
    __bf16* ctxTl = ctxTh + CTXT;
    float*  kcumT = (float*)(ctxTl + CTXT);
    float*  diag  = kcumT + 8192;
    float*  parts = diag + (size_t)B_ * HEADS_ * N_;
    float*  stab  = parts + 2048;
    float*  ctxp  = stab + 16;
    float*  kcump = ctxp + (size_t)NSPLIT * CTXT;

    __bf16 *WoH = WH + 3*WSZ, *WoL = WL + 3*WSZ;

    // 0) splits
    split_bf16<<<QSZ / 4 / 256, 256, 0, stream>>>(hs, hsH, hsL);
    split_w<<<dim3(WSZ / 4 / 256, 4), 256, 0, stream>>>(Wq, Wk, Wv, Wo, WH, WL);
    split_bf16<<<(M_ * DH_) / 4 / 256, 256, 0, stream>>>(proj, projH, projL);

    // 1) merged Q,K,V = hs @ {Wq,Wk,Wv}^T + b  -> bf16 hi/lo
    gemm_qkv<<<dim3(H_ / 128, (B_ * N_) / 128), 512, 0, stream>>>(
        hsH, hsL, WH, WL, bq, bk, bv, Qh, Ql, Kh, Kl, Vh, Vl);

    // 2) diag + global stabilizer
    diag_kernel<<<2048, 256, 0, stream>>>(Kh, Kl, diag, parts);
    reduce_stab<<<1, 256, 0, stream>>>(parts, stab, 2048);

    // 3) ctx partials (MFMA) + kcum partials
    ctx_mfma<<<dim3(NSPLIT, 2, B_ * HEADS_), 256, 0, stream>>>(
        Kh, Kl, Vh, Vl, projH, projL, diag, stab, ctxp, kcump);

    // 4) reduce partials -> bf16 ctxT + fp32 kcumT
    ctx_reduce<<<2048 + 32, 256, 0, stream>>>(ctxp, kcump, ctxTh, ctxTl, kcumT);

    // 5) out (MFMA), 512 thr / 8 waves, ctxT staged in LDS, fp32 denom
    out_mfma<<<dim3(N_ / 256, B_ * HEADS_), 512, 0, stream>>>(
        Qh, Ql, projH, projL, ctxTh, ctxTl, kcumT, hsH, hsL);

    // 6) final projection fp32 out
    gemm_out<<<dim3(H_ / 128, (B_ * N_) / 128), 512, 0, stream>>>(
        hsH, hsL, WoH, WoL, bo, out);
}

// Round 11
// 411.032 us; speedup vs baseline: 1.0577x; 1.0577x over previous
//
#include <hip/hip_runtime.h>
#include <math.h>

#define B_      2
#define N_      4096
#define H_      1024
#define HEADS_  16
#define DH_     64
#define M_      256
#define NSPLIT  8
#define EPAD    80

constexpr float NORMALIZER = 0.35355339059327373f; // 64^-0.25
constexpr float RATIO      = 0.0625f;              // 256^-0.5
constexpr float KEPS       = 1e-3f;

typedef __bf16 bf16x8 __attribute__((ext_vector_type(8)));
typedef __bf16 bf16x4 __attribute__((ext_vector_type(4)));
typedef float  f32x4  __attribute__((ext_vector_type(4)));

// ======================================================================
// Split fp32 -> bf16 (hi, lo)
// ======================================================================
__global__ __launch_bounds__(256) void split_bf16(
    const float* __restrict__ src, __bf16* __restrict__ hi, __bf16* __restrict__ lo)
{
    int i = blockIdx.x * 256 + threadIdx.x;
    float4 v = ((const float4*)src)[i];
    float vv[4] = {v.x, v.y, v.z, v.w};
    bf16x4 h, l;
#pragma unroll
    for (int j = 0; j < 4; ++j) {
        __bf16 hh = (__bf16)vv[j];
        h[j] = hh;
        l[j] = (__bf16)(vv[j] - (float)hh);
    }
    ((bf16x4*)hi)[i] = h;
    ((bf16x4*)lo)[i] = l;
}

__global__ __launch_bounds__(256) void split_w(
    const float* __restrict__ W0, const float* __restrict__ W1,
    const float* __restrict__ W2, const float* __restrict__ W3,
    __bf16* __restrict__ hi, __bf16* __restrict__ lo)
{
    const float* src = W0;
    if (blockIdx.y == 1) src = W1;
    else if (blockIdx.y == 2) src = W2;
    else if (blockIdx.y == 3) src = W3;
    int i = blockIdx.x * 256 + threadIdx.x;
    size_t o = (size_t)blockIdx.y * 262144 + i;
    float4 v = ((const float4*)src)[i];
    float vv[4] = {v.x, v.y, v.z, v.w};
    bf16x4 h, l;
#pragma unroll
    for (int j = 0; j < 4; ++j) {
        __bf16 hh = (__bf16)vv[j];
        h[j] = hh;
        l[j] = (__bf16)(vv[j] - (float)hh);
    }
    ((bf16x4*)hi)[o] = h;
    ((bf16x4*)lo)[o] = l;
}

// ======================================================================
// MERGED QKV GEMM with ROLE-STAGGERED 3-PHASE schedule (T3/T4/T5).
// Round-9 verified: 138.5 us best draw, MfmaUtil 50.9 (cross-run band
// 138-149). Staggered per-role vmcnt waits, no collective drain point.
// ======================================================================
__global__ __launch_bounds__(512, 2) void gemm_qkv(
    const __bf16* __restrict__ Ah, const __bf16* __restrict__ Al,
    const __bf16* __restrict__ WH, const __bf16* __restrict__ WL,   // [3][H*H] packed Q,K,V
    const float* __restrict__ bq, const float* __restrict__ bk, const float* __restrict__ bv,
    __bf16* __restrict__ Qh, __bf16* __restrict__ Ql,
    __bf16* __restrict__ Kh, __bf16* __restrict__ Kl,
    __bf16* __restrict__ Vh, __bf16* __restrict__ Vl)
{
    __shared__ alignas(16) __bf16 lds[2][8][128 * 32];

    const int t    = threadIdx.x;
    const int lane = t & 63;
    const int lm   = lane & 15;
    const int lq   = lane >> 4;
    const int w    = t >> 6;
    const int wm   = (w >> 2) * 64;    // m half
    const int wn   = (w & 3) * 32;     // n quarter

    const int wg = blockIdx.x + 8 * blockIdx.y;
    const int sw = (wg & 7) * 64 + (wg >> 3);
    const int n0 = (sw & 7) * 128;
    const int m0 = (sw >> 3) * 128;
    const int K  = 1024;
    const int NK = 32;
    const size_t WSZ = (size_t)H_ * H_;

    const __bf16* mysrc;
    if      (w == 0) mysrc = Ah;
    else if (w == 1) mysrc = Al;
    else             mysrc = ((w & 1) ? WL : WH) + (size_t)((w - 2) >> 1) * WSZ;
    const int rbase  = (w < 2) ? m0 : n0;
    const int rsub   = lane >> 2;
    const int slot   = lane & 3;
    const int schunk = slot ^ ((lane >> 3) & 3);
    const __bf16* gbase = mysrc + (size_t)(rbase + rsub) * K + schunk * 8;

    f32x4 acc[3][4][2];
#pragma unroll
    for (int s = 0; s < 3; ++s)
#pragma unroll
        for (int i = 0; i < 4; ++i)
#pragma unroll
            for (int j = 0; j < 2; ++j) acc[s][i][j] = (f32x4){0.f, 0.f, 0.f, 0.f};

    const int swz = (lq ^ ((lm >> 1) & 3)) * 8;

    auto stage = [&](int buf, int k0) {
#pragma unroll
        for (int c = 0; c < 8; ++c) {
            const __bf16* g = gbase + (size_t)c * 16 * K + k0;
            __builtin_amdgcn_global_load_lds(
                (const __attribute__((address_space(1))) void*)g,
                (__attribute__((address_space(3))) void*)&lds[buf][w][c * 512],
                16, 0, 0);
        }
    };

#define MFMA_S(S) \
    _Pragma("unroll") \
    for (int i = 0; i < 4; ++i) \
        _Pragma("unroll") \
        for (int j = 0; j < 2; ++j) { \
            acc[S][i][j] = __builtin_amdgcn_mfma_f32_16x16x32_bf16(ah[i], bh[j], acc[S][i][j], 0, 0, 0); \
            acc[S][i][j] = __builtin_amdgcn_mfma_f32_16x16x32_bf16(al[i], bh[j], acc[S][i][j], 0, 0, 0); \
            acc[S][i][j] = __builtin_amdgcn_mfma_f32_16x16x32_bf16(ah[i], bl[j], acc[S][i][j], 0, 0, 0); \
        }

    stage(0, 0);
    int p = 0;
#pragma unroll 1
    for (int kt = 0; kt < NK; ++kt) {
        const int nb  = p ^ 1;
        const int nk0 = (kt + 1) * 32;
        const bool more = (kt < NK - 1);
        bf16x8 ah[4], al[4], bh[2], bl[2];

        // ---- P1: A + Wq (owners 0-3) ----
        if (w < 4) asm volatile("s_waitcnt vmcnt(0)" ::: "memory");
        asm volatile("s_barrier" ::: "memory");
#pragma unroll
        for (int i = 0; i < 4; ++i) {
            int off = (wm + i * 16 + lm) * 32 + swz;
            ah[i] = *(const bf16x8*)&lds[p][0][off];
            al[i] = *(const bf16x8*)&lds[p][1][off];
        }
#pragma unroll
        for (int j = 0; j < 2; ++j) {
            int off = (wn + j * 16 + lm) * 32 + swz;
            bh[j] = *(const bf16x8*)&lds[p][2][off];
            bl[j] = *(const bf16x8*)&lds[p][3][off];
        }
        if (more && w < 4) stage(nb, nk0);
        asm volatile("s_waitcnt lgkmcnt(0)" ::: "memory");
        __builtin_amdgcn_sched_barrier(0);
        __builtin_amdgcn_s_setprio(1);
        MFMA_S(0)
        __builtin_amdgcn_s_setprio(0);

        // ---- P2: Wk (owners 4-5) ----
        if (w == 4 || w == 5) asm volatile("s_waitcnt vmcnt(0)" ::: "memory");
        asm volatile("s_barrier" ::: "memory");
#pragma unroll
        for (int j = 0; j < 2; ++j) {
            int off = (wn + j * 16 + lm) * 32 + swz;
            bh[j] = *(const bf16x8*)&lds[p][4][off];
            bl[j] = *(const bf16x8*)&lds[p][5][off];
        }
        if (more && (w == 4 || w == 5)) stage(nb, nk0);
        asm volatile("s_waitcnt lgkmcnt(0)" ::: "memory");
        __builtin_amdgcn_sched_barrier(0);
        __builtin_amdgcn_s_setprio(1);
        MFMA_S(1)
        __builtin_amdgcn_s_setprio(0);

        // ---- P3: Wv (owners 6-7) ----
        if (w >= 6) asm volatile("s_waitcnt vmcnt(0)" ::: "memory");
        asm volatile("s_barrier" ::: "memory");
#pragma unroll
        for (int j = 0; j < 2; ++j) {
            int off = (wn + j * 16 + lm) * 32 + swz;
            bh[j] = *(const bf16x8*)&lds[p][6][off];
            bl[j] = *(const bf16x8*)&lds[p][7][off];
        }
        if (more && w >= 6) stage(nb, nk0);
        asm volatile("s_waitcnt lgkmcnt(0)" ::: "memory");
        __builtin_amdgcn_sched_barrier(0);
        __builtin_amdgcn_s_setprio(1);
        MFMA_S(2)
        __builtin_amdgcn_s_setprio(0);

        p ^= 1;
    }
#undef MFMA_S

    const float* biases[3] = {bq, bk, bv};
    __bf16* Chs[3] = {Qh, Kh, Vh};
    __bf16* Cls[3] = {Ql, Kl, Vl};
#pragma unroll
    for (int s = 0; s < 3; ++s) {
        float bsr[2];
#pragma unroll
        for (int j = 0; j < 2; ++j) bsr[j] = biases[s][n0 + wn + j * 16 + lm];
#pragma unroll
        for (int i = 0; i < 4; ++i)
#pragma unroll
            for (int r = 0; r < 4; ++r) {
                int rowm = m0 + wm + i * 16 + lq * 4 + r;
#pragma unroll
                for (int j = 0; j < 2; ++j) {
                    int col = n0 + wn + j * 16 + lm;
                    float o = acc[s][i][j][r] + bsr[j];
                    __bf16 hh = (__bf16)o;
                    Chs[s][(size_t)rowm * 1024 + col] = hh;
                    Cls[s][(size_t)rowm * 1024 + col] = (__bf16)(o - (float)hh);
                }
            }
    }
}

// ======================================================================
// Final projection GEMM (round-2 verified schedule + T1). UNCHANGED.
// ======================================================================
__global__ __launch_bounds__(512, 4) void gemm_out(
    const __bf16* __restrict__ Ah, const __bf16* __restrict__ Al,
    const __bf16* __restrict__ Bh, const __bf16* __restrict__ Bl,
    const float* __restrict__ bias, float* __restrict__ C0)
{
    __shared__ alignas(16) __bf16 lds[2][4][128 * 32];

    const int t    = threadIdx.x;
    const int lane = t & 63;
    const int lm   = lane & 15;
    const int lq   = lane >> 4;
    const int w    = t >> 6;
    const int wm   = (w >> 2) * 64;
    const int wn   = (w & 3) * 32;

    const int wg = blockIdx.x + 8 * blockIdx.y;
    const int sw = (wg & 7) * 64 + (wg >> 3);
    const int n0 = (sw & 7) * 128;
    const int m0 = (sw >> 3) * 128;
    const int K  = 1024;
    const int NK = 32;

    const int tw = w >> 1;
    const int hw = w & 1;
    const __bf16* mysrc = (tw == 0) ? Ah : (tw == 1) ? Al : (tw == 2) ? Bh : Bl;
    const int     rbase = ((tw < 2) ? m0 : n0) + hw * 64;
    const int rsub   = lane >> 2;
    const int slot   = lane & 3;
    const int schunk = slot ^ ((lane >> 3) & 3);
    const __bf16* gbase = mysrc + (size_t)(rbase + rsub) * K + schunk * 8;

    f32x4 acc[4][2];
#pragma unroll
    for (int i = 0; i < 4; ++i)
#pragma unroll
        for (int j = 0; j < 2; ++j) acc[i][j] = (f32x4){0.f, 0.f, 0.f, 0.f};

    const int swz = (lq ^ ((lm >> 1) & 3)) * 8;

    auto stage = [&](int buf, int k0) {
#pragma unroll
        for (int c = 0; c < 4; ++c) {
            const __bf16* g = gbase + (size_t)c * 16 * K + k0;
            __builtin_amdgcn_global_load_lds(
                (const __attribute__((address_space(1))) void*)g,
                (__attribute__((address_space(3))) void*)&lds[buf][tw][(hw * 64 + c * 16) * 32],
                16, 0, 0);
        }
    };

    auto compute = [&](int p) {
        const __bf16* tAh = lds[p][0];
        const __bf16* tAl = lds[p][1];
        const __bf16* tBh = lds[p][2];
        const __bf16* tBl = lds[p][3];
        bf16x8 bh[2], bl[2];
#pragma unroll
        for (int j = 0; j < 2; ++j) {
            int off = (wn + j * 16 + lm) * 32 + swz;
            bh[j] = *(const bf16x8*)&tBh[off];
            bl[j] = *(const bf16x8*)&tBl[off];
        }
#pragma unroll
        for (int i = 0; i < 4; ++i) {
            int off = (wm + i * 16 + lm) * 32 + swz;
            bf16x8 ah = *(const bf16x8*)&tAh[off];
            bf16x8 al = *(const bf16x8*)&tAl[off];
#pragma unroll
            for (int j = 0; j < 2; ++j) {
                acc[i][j] = __builtin_amdgcn_mfma_f32_16x16x32_bf16(ah, bh[j], acc[i][j], 0, 0, 0);
                acc[i][j] = __builtin_amdgcn_mfma_f32_16x16x32_bf16(al, bh[j], acc[i][j], 0, 0, 0);
                acc[i][j] = __builtin_amdgcn_mfma_f32_16x16x32_bf16(ah, bl[j], acc[i][j], 0, 0, 0);
            }
        }
    };

    stage(0, 0);
    int p = 0;
#pragma unroll 1
    for (int kk = 0; kk < NK - 1; ++kk) {
        stage(p ^ 1, (kk + 1) * 32);
        asm volatile("s_waitcnt vmcnt(4)" ::: "memory");
        asm volatile("s_barrier" ::: "memory");
        compute(p);
        asm volatile("s_barrier" ::: "memory");
        p ^= 1;
    }
    asm volatile("s_waitcnt vmcnt(0)" ::: "memory");
    asm volatile("s_barrier" ::: "memory");
    compute(p);

    float bsr[2];
#pragma unroll
    for (int j = 0; j < 2; ++j) bsr[j] = bias[n0 + wn + j * 16 + lm];
#pragma unroll
    for (int i = 0; i < 4; ++i)
#pragma unroll
        for (int r = 0; r < 4; ++r) {
            int rowm = m0 + wm + i * 16 + lq * 4 + r;
#pragma unroll
            for (int j = 0; j < 2; ++j) {
                int col = n0 + wn + j * 16 + lm;
                C0[(size_t)rowm * 1024 + col] = acc[i][j][r] + bsr[j];
            }
        }
}

// ======================================================================
// diag_k from bf16 hi/lo K
// ======================================================================
__global__ __launch_bounds__(256) void diag_kernel(
    const __bf16* __restrict__ Kh, const __bf16* __restrict__ Kl,
    float* __restrict__ diag, float* __restrict__ partials)
{
    int gt = blockIdx.x * 256 + threadIdx.x;
    int r  = gt >> 2;
    int q  = gt & 3;
    const bf16x8* ph = (const bf16x8*)(Kh + (size_t)r * 64 + q * 16);
    const bf16x8* pl = (const bf16x8*)(Kl + (size_t)r * 64 + q * 16);
    float s = 0.f;
#pragma unroll
    for (int i = 0; i < 2; ++i) {
        bf16x8 vh = ph[i], vl = pl[i];
#pragma unroll
        for (int j = 0; j < 8; ++j) {
            float x = (float)vh[j] + (float)vl[j];
            s += x * x;
        }
    }
    s += __shfl_xor(s, 1);
    s += __shfl_xor(s, 2);
    float d = -0.5f * s;
    if (q == 0) {
        int h = r & 15, bn = r >> 4;
        int n = bn & 4095, b = bn >> 12;
        diag[(((size_t)b * 16 + h) << 12) + n] = d;
    }
    __shared__ float red[256];
    red[threadIdx.x] = d;
    __syncthreads();
    for (int s2 = 128; s2 > 0; s2 >>= 1) {
        if (threadIdx.x < s2) red[threadIdx.x] = fmaxf(red[threadIdx.x], red[threadIdx.x + s2]);
        __syncthreads();
    }
    if (threadIdx.x == 0) partials[blockIdx.x] = red[0];
}

__global__ __launch_bounds__(256) void reduce_stab(
    const float* __restrict__ partials, float* __restrict__ stab, int n)
{
    float m = -3.0e38f;
    for (int i = threadIdx.x; i < n; i += 256) m = fmaxf(m, partials[i]);
    __shared__ float red[256];
    red[threadIdx.x] = m;
    __syncthreads();
    for (int s2 = 128; s2 > 0; s2 >>= 1) {
        if (threadIdx.x < s2) red[threadIdx.x] = fmaxf(red[threadIdx.x], red[threadIdx.x + s2]);
        __syncthreads();
    }
    if (threadIdx.x == 0) stab[0] = red[0];
}

// ======================================================================
// ctx via MFMA. T14 async prefetch for V, K, diag (rounds 6-8 verified).
// ======================================================================
__global__ __launch_bounds__(256, 2) void ctx_mfma(
    const __bf16* __restrict__ Kh, const __bf16* __restrict__ Kl,
    const __bf16* __restrict__ Vh, const __bf16* __restrict__ Vl,
    const __bf16* __restrict__ projH, const __bf16* __restrict__ projL,
    const float* __restrict__ diag, const float* __restrict__ stabp,
    float* __restrict__ ctxp)
{
    __shared__ alignas(16) char ldsbuf[59904];
    __shared__ float dg[64];
    __bf16* kfTh = (__bf16*)ldsbuf;              // [128][72]
    __bf16* kfTl = kfTh + 9216;                  // [128][72]
    __bf16* vTh  = kfTl + 9216;                  // [80][72]
    __bf16* vTl  = vTh + 5760;                   // [80][72]
    float*  ctxe = (float*)ldsbuf;               // [128][81] (epilogue alias)

    const int t    = threadIdx.x;
    const int lane = t & 63;
    const int w    = t >> 6;
    const int lm   = lane & 15;
    const int lq   = lane >> 4;
    const int bh   = blockIdx.z;
    const int b    = bh >> 4, h = bh & 15;
    const int mh   = blockIdx.y;
    const int slice = blockIdx.x;
    const int mwave = mh * 128 + w * 32;
    const float stab = stabp[0];
    const size_t rowbase = (size_t)b * N_ * H_ + (size_t)h * DH_;
    const float* diag_bh = diag + (size_t)bh * N_;

    for (int idx = t; idx < 16 * 72; idx += 256) {
        int e = 64 + idx / 72, n = idx % 72;
        vTh[e * 72 + n] = (e == 64 && n < 64) ? (__bf16)1.0f : (__bf16)0.0f;
        vTl[e * 72 + n] = (__bf16)0.0f;
    }

    bf16x8 ph[2][2], pl[2][2];
#pragma unroll
    for (int mf = 0; mf < 2; ++mf)
#pragma unroll
        for (int ks = 0; ks < 2; ++ks) {
            size_t pa = (size_t)(mwave + mf * 16 + lm) * 64 + ks * 32 + lq * 8;
            ph[mf][ks] = *(const bf16x8*)(projH + pa);
            pl[mf][ks] = *(const bf16x8*)(projL + pa);
        }

    f32x4 acc[2][5];
#pragma unroll
    for (int mf = 0; mf < 2; ++mf)
#pragma unroll
        for (int ef = 0; ef < 5; ++ef) acc[mf][ef] = (f32x4){0.f, 0.f, 0.f, 0.f};

    const int nl = t >> 2, dc = (t & 3) * 16;
    bf16x8 v0, v1, u0, u1;
    bf16x8 kh_p[4][2], kl_p[4][2];
    float dgr = 0.f;
    {
        const int nbase = slice * (N_ / NSPLIT);
        size_t va = rowbase + (size_t)(nbase + nl) * H_ + dc;
        v0 = *(const bf16x8*)(Vh + va);
        v1 = *(const bf16x8*)(Vh + va + 8);
        u0 = *(const bf16x8*)(Vl + va);
        u1 = *(const bf16x8*)(Vl + va + 8);
#pragma unroll
        for (int nf = 0; nf < 4; ++nf)
#pragma unroll
            for (int ks = 0; ks < 2; ++ks) {
                size_t ka = rowbase + (size_t)(nbase + nf * 16 + lm) * H_ + ks * 32 + lq * 8;
                kh_p[nf][ks] = *(const bf16x8*)(Kh + ka);
                kl_p[nf][ks] = *(const bf16x8*)(Kl + ka);
            }
        if (t < 64) dgr = diag_bh[nbase + t];
    }

    for (int tile = 0; tile < 8; ++tile) {
        const int n0 = slice * (N_ / NSPLIT) + tile * 64;
        __syncthreads();   // barrier A

#pragma unroll
        for (int j = 0; j < 8; ++j) {
            vTh[(dc + j) * 72 + nl]     = v0[j];
            vTh[(dc + 8 + j) * 72 + nl] = v1[j];
            vTl[(dc + j) * 72 + nl]     = u0[j];
            vTl[(dc + 8 + j) * 72 + nl] = u1[j];
        }
        if (t < 64) dg[t] = dgr - stab;

        f32x4 dsh[4][2];
#pragma unroll
        for (int nf = 0; nf < 4; ++nf) {
#pragma unroll
            for (int mf = 0; mf < 2; ++mf) dsh[nf][mf] = (f32x4){0.f, 0.f, 0.f, 0.f};
#pragma unroll
            for (int mf = 0; mf < 2; ++mf)
#pragma unroll
                for (int ks = 0; ks < 2; ++ks) {
                    dsh[nf][mf] = __builtin_amdgcn_mfma_f32_16x16x32_bf16(kh_p[nf][ks], ph[mf][ks], dsh[nf][mf], 0, 0, 0);
                    dsh[nf][mf] = __builtin_amdgcn_mfma_f32_16x16x32_bf16(kl_p[nf][ks], ph[mf][ks], dsh[nf][mf], 0, 0, 0);
                    dsh[nf][mf] = __builtin_amdgcn_mfma_f32_16x16x32_bf16(kh_p[nf][ks], pl[mf][ks], dsh[nf][mf], 0, 0, 0);
                }
        }

        __syncthreads();   // barrier B

        if (tile < 7) {
            size_t va = rowbase + (size_t)(n0 + 64 + nl) * H_ + dc;
            v0 = *(const bf16x8*)(Vh + va);
            v1 = *(const bf16x8*)(Vh + va + 8);
            u0 = *(const bf16x8*)(Vl + va);
            u1 = *(const bf16x8*)(Vl + va + 8);
#pragma unroll
            for (int nf = 0; nf < 4; ++nf)
#pragma unroll
                for (int ks = 0; ks < 2; ++ks) {
                    size_t ka = rowbase + (size_t)(n0 + 64 + nf * 16 + lm) * H_ + ks * 32 + lq * 8;
                    kh_p[nf][ks] = *(const bf16x8*)(Kh + ka);
                    kl_p[nf][ks] = *(const bf16x8*)(Kl + ka);
                }
            if (t < 64) dgr = diag_bh[n0 + 64 + t];
        }

#pragma unroll
        for (int nf = 0; nf < 4; ++nf) {
            float4 dgv = *(const float4*)&dg[nf * 16 + lq * 4];
            float dga[4] = {dgv.x, dgv.y, dgv.z, dgv.w};
#pragma unroll
            for (int mf = 0; mf < 2; ++mf) {
                int mrow = w * 32 + mf * 16 + lm;
                bf16x4 vh_, vl_;
#pragma unroll
                for (int r = 0; r < 4; ++r) {
                    float kf = RATIO * (__expf(dga[r] + NORMALIZER * dsh[nf][mf][r]) + KEPS);
                    __bf16 hh = (__bf16)kf;
                    vh_[r] = hh;
                    vl_[r] = (__bf16)(kf - (float)hh);
                }
                int nbase = nf * 16 + lq * 4;
                *(bf16x4*)&kfTh[mrow * 72 + nbase] = vh_;
                *(bf16x4*)&kfTl[mrow * 72 + nbase] = vl_;
            }
        }

#pragma unroll
        for (int ks = 0; ks < 2; ++ks) {
#pragma unroll
            for (int mf = 0; mf < 2; ++mf) {
                bf16x8 af = *(const bf16x8*)&kfTh[(w * 32 + mf * 16 + lm) * 72 + ks * 32 + lq * 8];
                bf16x8 afl = *(const bf16x8*)&kfTl[(w * 32 + mf * 16 + lm) * 72 + ks * 32 + lq * 8];
#pragma unroll
                for (int ef = 0; ef < 5; ++ef) {
                    bf16x8 bfh = *(const bf16x8*)&vTh[(ef * 16 + lm) * 72 + ks * 32 + lq * 8];
                    bf16x8 bfl = *(const bf16x8*)&vTl[(ef * 16 + lm) * 72 + ks * 32 + lq * 8];
                    acc[mf][ef] = __builtin_amdgcn_mfma_f32_16x16x32_bf16(af,  bfh, acc[mf][ef], 0, 0, 0);
                    acc[mf][ef] = __builtin_amdgcn_mfma_f32_16x16x32_bf16(afl, bfh, acc[mf][ef], 0, 0, 0);
                    acc[mf][ef] = __builtin_amdgcn_mfma_f32_16x16x32_bf16(af,  bfl, acc[mf][ef], 0, 0, 0);
                }
            }
        }
    }

    __syncthreads();
#pragma unroll
    for (int mf = 0; mf < 2; ++mf)
#pragma unroll
        for (int ef = 0; ef < 5; ++ef)
#pragma unroll
            for (int r = 0; r < 4; ++r) {
                int ml = w * 32 + mf * 16 + lq * 4 + r;
                int e  = ef * 16 + lm;
                ctxe[ml * 81 + e] = acc[mf][ef][r];
            }
    __syncthreads();
    const size_t SLICE = (size_t)(B_ * HEADS_) * EPAD * M_;
    const size_t obase = (size_t)slice * SLICE + (size_t)bh * EPAD * M_;
    for (int i = t; i < EPAD * 128; i += 256) {
        int e = i >> 7, ml = i & 127;
        ctxp[obase + (size_t)e * M_ + mh * 128 + ml] = ctxe[ml * 81 + e];
    }
}

// ======================================================================
// Reduce ctx partials over slices -> bf16 hi/lo ctxT[bh][e][m]
// ======================================================================
__global__ __launch_bounds__(256) void ctx_reduce(
    const float* __restrict__ ctxp, __bf16* __restrict__ ctxTh, __bf16* __restrict__ ctxTl)
{
    int idx = blockIdx.x * 256 + threadIdx.x;
    const size_t SLICE = (size_t)(B_ * HEADS_) * EPAD * M_;
    float s = 0.f;
#pragma unroll
    for (int k = 0; k < NSPLIT; ++k) s += ctxp[(size_t)k * SLICE + idx];
    __bf16 hh = (__bf16)s;
    ctxTh[idx] = hh;
    ctxTl[idx] = (__bf16)(s - (float)hh);
}

// ======================================================================
// out via MFMA (round-8: ctx in LDS + proj reg double-buffer). UNCHANGED.
// ======================================================================
__global__ __launch_bounds__(512, 2) void out_mfma(
    const __bf16* __restrict__ Qh, const __bf16* __restrict__ Ql,
    const __bf16* __restrict__ projH, const __bf16* __restrict__ projL,
    const __bf16* __restrict__ ctxTh, const __bf16* __restrict__ ctxTl,
    __bf16* __restrict__ attnH, __bf16* __restrict__ attnL)
{
    __shared__ alignas(16) __bf16 ctxLh[80 * 256];
    __shared__ alignas(16) __bf16 ctxLl[80 * 256];
    __shared__ alignas(16) __bf16 qfh[8][32][72];
    __shared__ alignas(16) __bf16 qfl[8][32][72];

    const int t    = threadIdx.x;
    const int lane = t & 63;
    const int w    = t >> 6;
    const int lm   = lane & 15;
    const int lq   = lane >> 4;
    const int bh   = blockIdx.y;
    const int b    = bh >> 4, h = bh & 15;
    const int nw   = blockIdx.x * 256 + w * 32;
    const size_t rowbase = (size_t)b * N_ * H_ + (size_t)h * DH_;

    const __bf16* cth = ctxTh + (size_t)bh * EPAD * M_;
    const __bf16* ctl = ctxTl + (size_t)bh * EPAD * M_;

    {
        const int r_in = lane >> 5;
        const int cp   = lane & 31;
#pragma unroll
        for (int c = 0; c < 5; ++c) {
            int idx = w * 5 + c;
            int r   = idx * 2 + r_in;
            int gc  = cp ^ (r & 7);
            const __bf16* gh = cth + (size_t)r * 256 + gc * 8;
            const __bf16* gl = ctl + (size_t)r * 256 + gc * 8;
            __builtin_amdgcn_global_load_lds(
                (const __attribute__((address_space(1))) void*)gh,
                (__attribute__((address_space(3))) void*)&ctxLh[idx * 512],
                16, 0, 0);
            __builtin_amdgcn_global_load_lds(
                (const __attribute__((address_space(1))) void*)gl,
                (__attribute__((address_space(3))) void*)&ctxLl[idx * 512],
                16, 0, 0);
        }
    }

    bf16x8 qh_[2][2], ql_[2][2];
#pragma unroll
    for (int nf = 0; nf < 2; ++nf)
#pragma unroll
        for (int ks = 0; ks < 2; ++ks) {
            size_t qa = rowbase + (size_t)(nw + nf * 16 + lm) * H_ + ks * 32 + lq * 8;
            qh_[nf][ks] = *(const bf16x8*)(Qh + qa);
            ql_[nf][ks] = *(const bf16x8*)(Ql + qa);
        }
    bf16x8 pc_h[4][2], pc_l[4][2];
#pragma unroll
    for (int mf = 0; mf < 4; ++mf)
#pragma unroll
        for (int ks = 0; ks < 2; ++ks) {
            size_t pa = (size_t)(mf * 16 + lm) * 64 + ks * 32 + lq * 8;
            pc_h[mf][ks] = *(const bf16x8*)(projH + pa);
            pc_l[mf][ks] = *(const bf16x8*)(projL + pa);
        }

    __syncthreads();

    f32x4 accO[2][5];
#pragma unroll
    for (int nf = 0; nf < 2; ++nf)
#pragma unroll
        for (int ef = 0; ef < 5; ++ef) accO[nf][ef] = (f32x4){0.f, 0.f, 0.f, 0.f};

#pragma unroll
    for (int mc = 0; mc < 4; ++mc) {
        const int m0 = mc * 64;
        f32x4 dsh[2][4];
#pragma unroll
        for (int nf = 0; nf < 2; ++nf)
#pragma unroll
            for (int mf = 0; mf < 4; ++mf) dsh[nf][mf] = (f32x4){0.f, 0.f, 0.f, 0.f};
#pragma unroll
        for (int mf = 0; mf < 4; ++mf)
#pragma unroll
            for (int ks = 0; ks < 2; ++ks)
#pragma unroll
                for (int nf = 0; nf < 2; ++nf) {
                    dsh[nf][mf] = __builtin_amdgcn_mfma_f32_16x16x32_bf16(qh_[nf][ks], pc_h[mf][ks], dsh[nf][mf], 0, 0, 0);
                    dsh[nf][mf] = __builtin_amdgcn_mfma_f32_16x16x32_bf16(ql_[nf][ks], pc_h[mf][ks], dsh[nf][mf], 0, 0, 0);
                    dsh[nf][mf] = __builtin_amdgcn_mfma_f32_16x16x32_bf16(qh_[nf][ks], pc_l[mf][ks], dsh[nf][mf], 0, 0, 0);
                }
        bf16x8 pn_h[4][2], pn_l[4][2];
        if (mc < 3) {
#pragma unroll
            for (int mf = 0; mf < 4; ++mf)
#pragma unroll
                for (int ks = 0; ks < 2; ++ks) {
                    size_t pa = (size_t)((m0 + 64) + mf * 16 + lm) * 64 + ks * 32 + lq * 8;
                    pn_h[mf][ks] = *(const bf16x8*)(projH + pa);
                    pn_l[mf][ks] = *(const bf16x8*)(projL + pa);
                }
        }
#pragma unroll
        for (int nf = 0; nf < 2; ++nf)
#pragma unroll
            for (int mf = 0; mf < 4; ++mf)
#pragma unroll
                for (int r = 0; r < 4; ++r) {
                    float qf = RATIO * (__expf(NORMALIZER * dsh[nf][mf][r]) + KEPS);
                    __bf16 hh = (__bf16)qf;
                    int nloc = nf * 16 + lq * 4 + r;
                    qfh[w][nloc][mf * 16 + lm] = hh;
                    qfl[w][nloc][mf * 16 + lm] = (__bf16)(qf - (float)hh);
                }
#pragma unroll
        for (int ks = 0; ks < 2; ++ks) {
            bf16x8 af[2], afl[2];
#pragma unroll
            for (int nf = 0; nf < 2; ++nf) {
                af[nf]  = *(const bf16x8*)&qfh[w][nf * 16 + lm][ks * 32 + lq * 8];
                afl[nf] = *(const bf16x8*)&qfl[w][nf * 16 + lm][ks * 32 + lq * 8];
            }
#pragma unroll
            for (int ef = 0; ef < 5; ++ef) {
                int row = ef * 16 + lm;
                int sc  = ((m0 >> 3) + ks * 4 + lq) ^ (lm & 7);
                int off = row * 256 + sc * 8;
                bf16x8 bfh = *(const bf16x8*)&ctxLh[off];
                bf16x8 bfl = *(const bf16x8*)&ctxLl[off];
#pragma unroll
                for (int nf = 0; nf < 2; ++nf) {
                    accO[nf][ef] = __builtin_amdgcn_mfma_f32_16x16x32_bf16(af[nf],  bfh, accO[nf][ef], 0, 0, 0);
                    accO[nf][ef] = __builtin_amdgcn_mfma_f32_16x16x32_bf16(afl[nf], bfh, accO[nf][ef], 0, 0, 0);
                    accO[nf][ef] = __builtin_amdgcn_mfma_f32_16x16x32_bf16(af[nf],  bfl, accO[nf][ef], 0, 0, 0);
                }
            }
        }
        if (mc < 3) {
#pragma unroll
            for (int mf = 0; mf < 4; ++mf)
#pragma unroll
                for (int ks = 0; ks < 2; ++ks) {
                    pc_h[mf][ks] = pn_h[mf][ks];
                    pc_l[mf][ks] = pn_l[mf][ks];
                }
        }
    }

#pragma unroll
    for (int nf = 0; nf < 2; ++nf) {
        float dinv[4];
#pragma unroll
        for (int r = 0; r < 4; ++r) {
            float den = __shfl(accO[nf][4][r], lane & 48);
            dinv[r] = 1.f / den;
        }
#pragma unroll
        for (int ef = 0; ef < 4; ++ef)
#pragma unroll
            for (int r = 0; r < 4; ++r) {
                float o = accO[nf][ef][r] * dinv[r];
                __bf16 hh = (__bf16)o;
                size_t oa = rowbase + (size_t)(nw + nf * 16 + lq * 4 + r) * H_ + ef * 16 + lm;
                attnH[oa] = hh;
                attnL[oa] = (__bf16)(o - (float)hh);
            }
    }
}

// ======================================================================
extern "C" void kernel_launch(void* const* d_in, const int* in_sizes, int n_in,
                              void* d_out, int out_size, void* d_ws, size_t ws_size,
                              hipStream_t stream) {
    const float* hs   = (const float*)d_in[0];
    const float* Wq   = (const float*)d_in[1];
    const float* bq   = (const float*)d_in[2];
    const float* Wk   = (const float*)d_in[3];
    const float* bk   = (const float*)d_in[4];
    const float* Wv   = (const float*)d_in[5];
    const float* bv   = (const float*)d_in[6];
    const float* Wo   = (const float*)d_in[7];
    const float* bo   = (const float*)d_in[8];
    const float* proj = (const float*)d_in[9];
    float* out = (float*)d_out;

    const size_t QSZ = (size_t)B_ * N_ * H_;           // 8388608
    const size_t WSZ = (size_t)H_ * H_;                // 1048576
    const size_t CTXT = (size_t)B_ * HEADS_ * EPAD * M_;  // 655360

    __bf16* Qh  = (__bf16*)d_ws;
    __bf16* Ql  = Qh + QSZ;
    __bf16* Kh  = Ql + QSZ;
    __bf16* Kl  = Kh + QSZ;
    __bf16* Vh  = Kl + QSZ;
    __bf16* Vl  = Vh + QSZ;
    __bf16* hsH = Vl + QSZ;      // aliased as attnH after hs consumed
    __bf16* hsL = hsH + QSZ;     // aliased as attnL
    __bf16* WH  = hsL + QSZ;
    __bf16* WL  = WH + 4 * WSZ;
    __bf16* projH = WL + 4 * WSZ;
    __bf16* projL = projH + (size_t)M_ * DH_;
    __bf16* ctxTh = projL + (size_t)M_ * DH_;
    __bf16* ctxTl = ctxTh + CTXT;
    float*  diag  = (float*)(ctxTl + CTXT);
    float*  parts = diag + (size_t)B_ * HEADS_ * N_;
    float*  stab  = parts + 2048;
    float*  ctxp  = stab + 16;

    __bf16 *WoH = WH + 3*WSZ, *WoL = WL + 3*WSZ;

    // 0) splits
    split_bf16<<<QSZ / 4 / 256, 256, 0, stream>>>(hs, hsH, hsL);
    split_w<<<dim3(WSZ / 4 / 256, 4), 256, 0, stream>>>(Wq, Wk, Wv, Wo, WH, WL);
    split_bf16<<<(M_ * DH_) / 4 / 256, 256, 0, stream>>>(proj, projH, projL);

    // 1) merged Q,K,V = hs @ {Wq,Wk,Wv}^T + b  -> bf16 hi/lo
    gemm_qkv<<<dim3(H_ / 128, (B_ * N_) / 128), 512, 0, stream>>>(
        hsH, hsL, WH, WL, bq, bk, bv, Qh, Ql, Kh, Kl, Vh, Vl);

    // 2) diag + global stabilizer
    diag_kernel<<<2048, 256, 0, stream>>>(Kh, Kl, diag, parts);
    reduce_stab<<<1, 256, 0, stream>>>(parts, stab, 2048);

    // 3) ctx partials (MFMA)
    ctx_mfma<<<dim3(NSPLIT, 2, B_ * HEADS_), 256, 0, stream>>>(
        Kh, Kl, Vh, Vl, projH, projL, diag, stab, ctxp);

    // 4) reduce partials -> bf16 ctxT
    ctx_reduce<<<(B_ * HEADS_ * EPAD * M_) / 256, 256, 0, stream>>>(ctxp, ctxTh, ctxTl);

    // 5) out (MFMA), 512 thr / 8 waves, ctxT staged in LDS
    out_mfma<<<dim3(N_ / 256, B_ * HEADS_), 512, 0, stream>>>(
        Qh, Ql, projH, projL, ctxTh, ctxTl, hsH, hsL);

    // 6) final projection fp32 out
    gemm_out<<<dim3(H_ / 128, (B_ * N_) / 128), 512, 0, stream>>>(
        hsH, hsL, WoH, WoL, bo, out);
}

// Round 12
// 402.552 us; speedup vs baseline: 1.0800x; 1.0211x over previous
//
#include <hip/hip_runtime.h>
#include <math.h>

#define B_      2
#define N_      4096
#define H_      1024
#define HEADS_  16
#define DH_     64
#define M_      256
#define NSPLIT  8
#define EPAD    80

constexpr float NORMALIZER = 0.35355339059327373f; // 64^-0.25
constexpr float RATIO      = 0.0625f;              // 256^-0.5
constexpr float KEPS       = 1e-3f;

typedef __bf16 bf16x8 __attribute__((ext_vector_type(8)));
typedef __bf16 bf16x4 __attribute__((ext_vector_type(4)));
typedef float  f32x4  __attribute__((ext_vector_type(4)));

// ======================================================================
// Split fp32 -> bf16 (hi, lo)
// ======================================================================
__global__ __launch_bounds__(256) void split_bf16(
    const float* __restrict__ src, __bf16* __restrict__ hi, __bf16* __restrict__ lo)
{
    int i = blockIdx.x * 256 + threadIdx.x;
    float4 v = ((const float4*)src)[i];
    float vv[4] = {v.x, v.y, v.z, v.w};
    bf16x4 h, l;
#pragma unroll
    for (int j = 0; j < 4; ++j) {
        __bf16 hh = (__bf16)vv[j];
        h[j] = hh;
        l[j] = (__bf16)(vv[j] - (float)hh);
    }
    ((bf16x4*)hi)[i] = h;
    ((bf16x4*)lo)[i] = l;
}

__global__ __launch_bounds__(256) void split_w(
    const float* __restrict__ W0, const float* __restrict__ W1,
    const float* __restrict__ W2, const float* __restrict__ W3,
    __bf16* __restrict__ hi, __bf16* __restrict__ lo)
{
    const float* src = W0;
    if (blockIdx.y == 1) src = W1;
    else if (blockIdx.y == 2) src = W2;
    else if (blockIdx.y == 3) src = W3;
    int i = blockIdx.x * 256 + threadIdx.x;
    size_t o = (size_t)blockIdx.y * 262144 + i;
    float4 v = ((const float4*)src)[i];
    float vv[4] = {v.x, v.y, v.z, v.w};
    bf16x4 h, l;
#pragma unroll
    for (int j = 0; j < 4; ++j) {
        __bf16 hh = (__bf16)vv[j];
        h[j] = hh;
        l[j] = (__bf16)(vv[j] - (float)hh);
    }
    ((bf16x4*)hi)[o] = h;
    ((bf16x4*)lo)[o] = l;
}

// ======================================================================
// MERGED QKV GEMM with ROLE-STAGGERED 3-PHASE schedule (T3/T4/T5).
// Round-9/11 verified: 138-149 us, MfmaUtil ~49-51. NEW this round:
// diag_k FUSED into the epilogue — each 128-col tile spans exactly 2
// heads' d-ranges, and K values exist in fp32 in acc[1] with bias, so
// diag = -0.5*sum(k^2) is computed exactly here: per-lane sq += o^2,
// shfl over lm (32-col wave partial), LDS pair-sum across the 2 waves
// per head, write diag + per-block max -> parts[wg]. Eliminates the
// separate diag_kernel (32 MB HBM re-read + launch).
// LDS scratch aliases staging buffer 0 (dead: last read kt=30, retired
// behind the kt=31 barriers; final reads are from buffer 1).
// ======================================================================
__global__ __launch_bounds__(512, 2) void gemm_qkv(
    const __bf16* __restrict__ Ah, const __bf16* __restrict__ Al,
    const __bf16* __restrict__ WH, const __bf16* __restrict__ WL,   // [3][H*H] packed Q,K,V
    const float* __restrict__ bq, const float* __restrict__ bk, const float* __restrict__ bv,
    __bf16* __restrict__ Qh, __bf16* __restrict__ Ql,
    __bf16* __restrict__ Kh, __bf16* __restrict__ Kl,
    __bf16* __restrict__ Vh, __bf16* __restrict__ Vl,
    float* __restrict__ diag, float* __restrict__ parts)
{
    __shared__ alignas(16) __bf16 lds[2][8][128 * 32];

    const int t    = threadIdx.x;
    const int lane = t & 63;
    const int lm   = lane & 15;
    const int lq   = lane >> 4;
    const int w    = t >> 6;
    const int wm   = (w >> 2) * 64;    // m half
    const int wn   = (w & 3) * 32;     // n quarter

    const int wg = blockIdx.x + 8 * blockIdx.y;
    const int sw = (wg & 7) * 64 + (wg >> 3);
    const int n0 = (sw & 7) * 128;
    const int m0 = (sw >> 3) * 128;
    const int K  = 1024;
    const int NK = 32;
    const size_t WSZ = (size_t)H_ * H_;

    const __bf16* mysrc;
    if      (w == 0) mysrc = Ah;
    else if (w == 1) mysrc = Al;
    else             mysrc = ((w & 1) ? WL : WH) + (size_t)((w - 2) >> 1) * WSZ;
    const int rbase  = (w < 2) ? m0 : n0;
    const int rsub   = lane >> 2;
    const int slot   = lane & 3;
    const int schunk = slot ^ ((lane >> 3) & 3);
    const __bf16* gbase = mysrc + (size_t)(rbase + rsub) * K + schunk * 8;

    f32x4 acc[3][4][2];
#pragma unroll
    for (int s = 0; s < 3; ++s)
#pragma unroll
        for (int i = 0; i < 4; ++i)
#pragma unroll
            for (int j = 0; j < 2; ++j) acc[s][i][j] = (f32x4){0.f, 0.f, 0.f, 0.f};

    const int swz = (lq ^ ((lm >> 1) & 3)) * 8;

    auto stage = [&](int buf, int k0) {
#pragma unroll
        for (int c = 0; c < 8; ++c) {
            const __bf16* g = gbase + (size_t)c * 16 * K + k0;
            __builtin_amdgcn_global_load_lds(
                (const __attribute__((address_space(1))) void*)g,
                (__attribute__((address_space(3))) void*)&lds[buf][w][c * 512],
                16, 0, 0);
        }
    };

#define MFMA_S(S) \
    _Pragma("unroll") \
    for (int i = 0; i < 4; ++i) \
        _Pragma("unroll") \
        for (int j = 0; j < 2; ++j) { \
            acc[S][i][j] = __builtin_amdgcn_mfma_f32_16x16x32_bf16(ah[i], bh[j], acc[S][i][j], 0, 0, 0); \
            acc[S][i][j] = __builtin_amdgcn_mfma_f32_16x16x32_bf16(al[i], bh[j], acc[S][i][j], 0, 0, 0); \
            acc[S][i][j] = __builtin_amdgcn_mfma_f32_16x16x32_bf16(ah[i], bl[j], acc[S][i][j], 0, 0, 0); \
        }

    stage(0, 0);
    int p = 0;
#pragma unroll 1
    for (int kt = 0; kt < NK; ++kt) {
        const int nb  = p ^ 1;
        const int nk0 = (kt + 1) * 32;
        const bool more = (kt < NK - 1);
        bf16x8 ah[4], al[4], bh[2], bl[2];

        // ---- P1: A + Wq (owners 0-3) ----
        if (w < 4) asm volatile("s_waitcnt vmcnt(0)" ::: "memory");
        asm volatile("s_barrier" ::: "memory");
#pragma unroll
        for (int i = 0; i < 4; ++i) {
            int off = (wm + i * 16 + lm) * 32 + swz;
            ah[i] = *(const bf16x8*)&lds[p][0][off];
            al[i] = *(const bf16x8*)&lds[p][1][off];
        }
#pragma unroll
        for (int j = 0; j < 2; ++j) {
            int off = (wn + j * 16 + lm) * 32 + swz;
            bh[j] = *(const bf16x8*)&lds[p][2][off];
            bl[j] = *(const bf16x8*)&lds[p][3][off];
        }
        if (more && w < 4) stage(nb, nk0);
        asm volatile("s_waitcnt lgkmcnt(0)" ::: "memory");
        __builtin_amdgcn_sched_barrier(0);
        __builtin_amdgcn_s_setprio(1);
        MFMA_S(0)
        __builtin_amdgcn_s_setprio(0);

        // ---- P2: Wk (owners 4-5) ----
        if (w == 4 || w == 5) asm volatile("s_waitcnt vmcnt(0)" ::: "memory");
        asm volatile("s_barrier" ::: "memory");
#pragma unroll
        for (int j = 0; j < 2; ++j) {
            int off = (wn + j * 16 + lm) * 32 + swz;
            bh[j] = *(const bf16x8*)&lds[p][4][off];
            bl[j] = *(const bf16x8*)&lds[p][5][off];
        }
        if (more && (w == 4 || w == 5)) stage(nb, nk0);
        asm volatile("s_waitcnt lgkmcnt(0)" ::: "memory");
        __builtin_amdgcn_sched_barrier(0);
        __builtin_amdgcn_s_setprio(1);
        MFMA_S(1)
        __builtin_amdgcn_s_setprio(0);

        // ---- P3: Wv (owners 6-7) ----
        if (w >= 6) asm volatile("s_waitcnt vmcnt(0)" ::: "memory");
        asm volatile("s_barrier" ::: "memory");
#pragma unroll
        for (int j = 0; j < 2; ++j) {
            int off = (wn + j * 16 + lm) * 32 + swz;
            bh[j] = *(const bf16x8*)&lds[p][6][off];
            bl[j] = *(const bf16x8*)&lds[p][7][off];
        }
        if (more && w >= 6) stage(nb, nk0);
        asm volatile("s_waitcnt lgkmcnt(0)" ::: "memory");
        __builtin_amdgcn_sched_barrier(0);
        __builtin_amdgcn_s_setprio(1);
        MFMA_S(2)
        __builtin_amdgcn_s_setprio(0);

        p ^= 1;
    }
#undef MFMA_S

    const float* biases[3] = {bq, bk, bv};
    __bf16* Chs[3] = {Qh, Kh, Vh};
    __bf16* Cls[3] = {Ql, Kl, Vl};
    float sq[4][4];
#pragma unroll
    for (int i = 0; i < 4; ++i)
#pragma unroll
        for (int r = 0; r < 4; ++r) sq[i][r] = 0.f;

#pragma unroll
    for (int s = 0; s < 3; ++s) {
        float bsr[2];
#pragma unroll
        for (int j = 0; j < 2; ++j) bsr[j] = biases[s][n0 + wn + j * 16 + lm];
#pragma unroll
        for (int i = 0; i < 4; ++i)
#pragma unroll
            for (int r = 0; r < 4; ++r) {
                int rowm = m0 + wm + i * 16 + lq * 4 + r;
#pragma unroll
                for (int j = 0; j < 2; ++j) {
                    int col = n0 + wn + j * 16 + lm;
                    float o = acc[s][i][j][r] + bsr[j];
                    if (s == 1) sq[i][r] += o * o;   // fused diag_k partial
                    __bf16 hh = (__bf16)o;
                    Chs[s][(size_t)rowm * 1024 + col] = hh;
                    Cls[s][(size_t)rowm * 1024 + col] = (__bf16)(o - (float)hh);
                }
            }
    }

    // ---- fused diag: reduce 32-col wave partials, pair-sum waves, write ----
    float* dsq = (float*)&lds[0][0][0];   // [8 waves][64 rows] = 2 KB (dead buffer 0)
    float* red = dsq + 512;               // [512]
#pragma unroll
    for (int i = 0; i < 4; ++i)
#pragma unroll
        for (int r = 0; r < 4; ++r) {
            float v = sq[i][r];
            v += __shfl_xor(v, 1);
            v += __shfl_xor(v, 2);
            v += __shfl_xor(v, 4);
            v += __shfl_xor(v, 8);
            if (lm == 0) dsq[w * 64 + i * 16 + lq * 4 + r] = v;
        }
    __syncthreads();
    float d = -3.0e38f;
    if (t < 256) {
        int rl   = t & 63;          // row within half
        int hsel = (t >> 6) & 1;    // head within tile
        int rh   = (t >> 7) & 1;    // row half (wm)
        float s2 = dsq[(rh * 4 + hsel * 2) * 64 + rl] + dsq[(rh * 4 + hsel * 2 + 1) * 64 + rl];
        d = -0.5f * s2;
        int rowm = m0 + rh * 64 + rl;
        int b = rowm >> 12, n = rowm & 4095;
        int head = (n0 >> 6) + hsel;
        diag[(((size_t)b * 16 + head) << 12) + n] = d;
    }
    red[t] = d;
    __syncthreads();
    for (int s2 = 256; s2 > 0; s2 >>= 1) {
        if (t < s2) red[t] = fmaxf(red[t], red[t + s2]);
        __syncthreads();
    }
    if (t == 0) parts[wg] = red[0];
}

// ======================================================================
// Final projection GEMM (round-2 verified schedule + T1). UNCHANGED.
// ======================================================================
__global__ __launch_bounds__(512, 4) void gemm_out(
    const __bf16* __restrict__ Ah, const __bf16* __restrict__ Al,
    const __bf16* __restrict__ Bh, const __bf16* __restrict__ Bl,
    const float* __restrict__ bias, float* __restrict__ C0)
{
    __shared__ alignas(16) __bf16 lds[2][4][128 * 32];

    const int t    = threadIdx.x;
    const int lane = t & 63;
    const int lm   = lane & 15;
    const int lq   = lane >> 4;
    const int w    = t >> 6;
    const int wm   = (w >> 2) * 64;
    const int wn   = (w & 3) * 32;

    const int wg = blockIdx.x + 8 * blockIdx.y;
    const int sw = (wg & 7) * 64 + (wg >> 3);
    const int n0 = (sw & 7) * 128;
    const int m0 = (sw >> 3) * 128;
    const int K  = 1024;
    const int NK = 32;

    const int tw = w >> 1;
    const int hw = w & 1;
    const __bf16* mysrc = (tw == 0) ? Ah : (tw == 1) ? Al : (tw == 2) ? Bh : Bl;
    const int     rbase = ((tw < 2) ? m0 : n0) + hw * 64;
    const int rsub   = lane >> 2;
    const int slot   = lane & 3;
    const int schunk = slot ^ ((lane >> 3) & 3);
    const __bf16* gbase = mysrc + (size_t)(rbase + rsub) * K + schunk * 8;

    f32x4 acc[4][2];
#pragma unroll
    for (int i = 0; i < 4; ++i)
#pragma unroll
        for (int j = 0; j < 2; ++j) acc[i][j] = (f32x4){0.f, 0.f, 0.f, 0.f};

    const int swz = (lq ^ ((lm >> 1) & 3)) * 8;

    auto stage = [&](int buf, int k0) {
#pragma unroll
        for (int c = 0; c < 4; ++c) {
            const __bf16* g = gbase + (size_t)c * 16 * K + k0;
            __builtin_amdgcn_global_load_lds(
                (const __attribute__((address_space(1))) void*)g,
                (__attribute__((address_space(3))) void*)&lds[buf][tw][(hw * 64 + c * 16) * 32],
                16, 0, 0);
        }
    };

    auto compute = [&](int p) {
        const __bf16* tAh = lds[p][0];
        const __bf16* tAl = lds[p][1];
        const __bf16* tBh = lds[p][2];
        const __bf16* tBl = lds[p][3];
        bf16x8 bh[2], bl[2];
#pragma unroll
        for (int j = 0; j < 2; ++j) {
            int off = (wn + j * 16 + lm) * 32 + swz;
            bh[j] = *(const bf16x8*)&tBh[off];
            bl[j] = *(const bf16x8*)&tBl[off];
        }
#pragma unroll
        for (int i = 0; i < 4; ++i) {
            int off = (wm + i * 16 + lm) * 32 + swz;
            bf16x8 ah = *(const bf16x8*)&tAh[off];
            bf16x8 al = *(const bf16x8*)&tAl[off];
#pragma unroll
            for (int j = 0; j < 2; ++j) {
                acc[i][j] = __builtin_amdgcn_mfma_f32_16x16x32_bf16(ah, bh[j], acc[i][j], 0, 0, 0);
                acc[i][j] = __builtin_amdgcn_mfma_f32_16x16x32_bf16(al, bh[j], acc[i][j], 0, 0, 0);
                acc[i][j] = __builtin_amdgcn_mfma_f32_16x16x32_bf16(ah, bl[j], acc[i][j], 0, 0, 0);
            }
        }
    };

    stage(0, 0);
    int p = 0;
#pragma unroll 1
    for (int kk = 0; kk < NK - 1; ++kk) {
        stage(p ^ 1, (kk + 1) * 32);
        asm volatile("s_waitcnt vmcnt(4)" ::: "memory");
        asm volatile("s_barrier" ::: "memory");
        compute(p);
        asm volatile("s_barrier" ::: "memory");
        p ^= 1;
    }
    asm volatile("s_waitcnt vmcnt(0)" ::: "memory");
    asm volatile("s_barrier" ::: "memory");
    compute(p);

    float bsr[2];
#pragma unroll
    for (int j = 0; j < 2; ++j) bsr[j] = bias[n0 + wn + j * 16 + lm];
#pragma unroll
    for (int i = 0; i < 4; ++i)
#pragma unroll
        for (int r = 0; r < 4; ++r) {
            int rowm = m0 + wm + i * 16 + lq * 4 + r;
#pragma unroll
            for (int j = 0; j < 2; ++j) {
                int col = n0 + wn + j * 16 + lm;
                C0[(size_t)rowm * 1024 + col] = acc[i][j][r] + bsr[j];
            }
        }
}

__global__ __launch_bounds__(256) void reduce_stab(
    const float* __restrict__ partials, float* __restrict__ stab, int n)
{
    float m = -3.0e38f;
    for (int i = threadIdx.x; i < n; i += 256) m = fmaxf(m, partials[i]);
    __shared__ float red[256];
    red[threadIdx.x] = m;
    __syncthreads();
    for (int s2 = 128; s2 > 0; s2 >>= 1) {
        if (threadIdx.x < s2) red[threadIdx.x] = fmaxf(red[threadIdx.x], red[threadIdx.x + s2]);
        __syncthreads();
    }
    if (threadIdx.x == 0) stab[0] = red[0];
}

// ======================================================================
// ctx via MFMA. T14 async prefetch for V, K, diag (rounds 6-8 verified).
// ======================================================================
__global__ __launch_bounds__(256, 2) void ctx_mfma(
    const __bf16* __restrict__ Kh, const __bf16* __restrict__ Kl,
    const __bf16* __restrict__ Vh, const __bf16* __restrict__ Vl,
    const __bf16* __restrict__ projH, const __bf16* __restrict__ projL,
    const float* __restrict__ diag, const float* __restrict__ stabp,
    float* __restrict__ ctxp)
{
    __shared__ alignas(16) char ldsbuf[59904];
    __shared__ float dg[64];
    __bf16* kfTh = (__bf16*)ldsbuf;              // [128][72]
    __bf16* kfTl = kfTh + 9216;                  // [128][72]
    __bf16* vTh  = kfTl + 9216;                  // [80][72]
    __bf16* vTl  = vTh + 5760;                   // [80][72]
    float*  ctxe = (float*)ldsbuf;               // [128][81] (epilogue alias)

    const int t    = threadIdx.x;
    const int lane = t & 63;
    const int w    = t >> 6;
    const int lm   = lane & 15;
    const int lq   = lane >> 4;
    const int bh   = blockIdx.z;
    const int b    = bh >> 4, h = bh & 15;
    const int mh   = blockIdx.y;
    const int slice = blockIdx.x;
    const int mwave = mh * 128 + w * 32;
    const float stab = stabp[0];
    const size_t rowbase = (size_t)b * N_ * H_ + (size_t)h * DH_;
    const float* diag_bh = diag + (size_t)bh * N_;

    for (int idx = t; idx < 16 * 72; idx += 256) {
        int e = 64 + idx / 72, n = idx % 72;
        vTh[e * 72 + n] = (e == 64 && n < 64) ? (__bf16)1.0f : (__bf16)0.0f;
        vTl[e * 72 + n] = (__bf16)0.0f;
    }

    bf16x8 ph[2][2], pl[2][2];
#pragma unroll
    for (int mf = 0; mf < 2; ++mf)
#pragma unroll
        for (int ks = 0; ks < 2; ++ks) {
            size_t pa = (size_t)(mwave + mf * 16 + lm) * 64 + ks * 32 + lq * 8;
            ph[mf][ks] = *(const bf16x8*)(projH + pa);
            pl[mf][ks] = *(const bf16x8*)(projL + pa);
        }

    f32x4 acc[2][5];
#pragma unroll
    for (int mf = 0; mf < 2; ++mf)
#pragma unroll
        for (int ef = 0; ef < 5; ++ef) acc[mf][ef] = (f32x4){0.f, 0.f, 0.f, 0.f};

    const int nl = t >> 2, dc = (t & 3) * 16;
    bf16x8 v0, v1, u0, u1;
    bf16x8 kh_p[4][2], kl_p[4][2];
    float dgr = 0.f;
    {
        const int nbase = slice * (N_ / NSPLIT);
        size_t va = rowbase + (size_t)(nbase + nl) * H_ + dc;
        v0 = *(const bf16x8*)(Vh + va);
        v1 = *(const bf16x8*)(Vh + va + 8);
        u0 = *(const bf16x8*)(Vl + va);
        u1 = *(const bf16x8*)(Vl + va + 8);
#pragma unroll
        for (int nf = 0; nf < 4; ++nf)
#pragma unroll
            for (int ks = 0; ks < 2; ++ks) {
                size_t ka = rowbase + (size_t)(nbase + nf * 16 + lm) * H_ + ks * 32 + lq * 8;
                kh_p[nf][ks] = *(const bf16x8*)(Kh + ka);
                kl_p[nf][ks] = *(const bf16x8*)(Kl + ka);
            }
        if (t < 64) dgr = diag_bh[nbase + t];
    }

    for (int tile = 0; tile < 8; ++tile) {
        const int n0 = slice * (N_ / NSPLIT) + tile * 64;
        __syncthreads();   // barrier A

#pragma unroll
        for (int j = 0; j < 8; ++j) {
            vTh[(dc + j) * 72 + nl]     = v0[j];
            vTh[(dc + 8 + j) * 72 + nl] = v1[j];
            vTl[(dc + j) * 72 + nl]     = u0[j];
            vTl[(dc + 8 + j) * 72 + nl] = u1[j];
        }
        if (t < 64) dg[t] = dgr - stab;

        f32x4 dsh[4][2];
#pragma unroll
        for (int nf = 0; nf < 4; ++nf) {
#pragma unroll
            for (int mf = 0; mf < 2; ++mf) dsh[nf][mf] = (f32x4){0.f, 0.f, 0.f, 0.f};
#pragma unroll
            for (int mf = 0; mf < 2; ++mf)
#pragma unroll
                for (int ks = 0; ks < 2; ++ks) {
                    dsh[nf][mf] = __builtin_amdgcn_mfma_f32_16x16x32_bf16(kh_p[nf][ks], ph[mf][ks], dsh[nf][mf], 0, 0, 0);
                    dsh[nf][mf] = __builtin_amdgcn_mfma_f32_16x16x32_bf16(kl_p[nf][ks], ph[mf][ks], dsh[nf][mf], 0, 0, 0);
                    dsh[nf][mf] = __builtin_amdgcn_mfma_f32_16x16x32_bf16(kh_p[nf][ks], pl[mf][ks], dsh[nf][mf], 0, 0, 0);
                }
        }

        __syncthreads();   // barrier B

        if (tile < 7) {
            size_t va = rowbase + (size_t)(n0 + 64 + nl) * H_ + dc;
            v0 = *(const bf16x8*)(Vh + va);
            v1 = *(const bf16x8*)(Vh + va + 8);
            u0 = *(const bf16x8*)(Vl + va);
            u1 = *(const bf16x8*)(Vl + va + 8);
#pragma unroll
            for (int nf = 0; nf < 4; ++nf)
#pragma unroll
                for (int ks = 0; ks < 2; ++ks) {
                    size_t ka = rowbase + (size_t)(n0 + 64 + nf * 16 + lm) * H_ + ks * 32 + lq * 8;
                    kh_p[nf][ks] = *(const bf16x8*)(Kh + ka);
                    kl_p[nf][ks] = *(const bf16x8*)(Kl + ka);
                }
            if (t < 64) dgr = diag_bh[n0 + 64 + t];
        }

#pragma unroll
        for (int nf = 0; nf < 4; ++nf) {
            float4 dgv = *(const float4*)&dg[nf * 16 + lq * 4];
            float dga[4] = {dgv.x, dgv.y, dgv.z, dgv.w};
#pragma unroll
            for (int mf = 0; mf < 2; ++mf) {
                int mrow = w * 32 + mf * 16 + lm;
                bf16x4 vh_, vl_;
#pragma unroll
                for (int r = 0; r < 4; ++r) {
                    float kf = RATIO * (__expf(dga[r] + NORMALIZER * dsh[nf][mf][r]) + KEPS);
                    __bf16 hh = (__bf16)kf;
                    vh_[r] = hh;
                    vl_[r] = (__bf16)(kf - (float)hh);
                }
                int nbase = nf * 16 + lq * 4;
                *(bf16x4*)&kfTh[mrow * 72 + nbase] = vh_;
                *(bf16x4*)&kfTl[mrow * 72 + nbase] = vl_;
            }
        }

#pragma unroll
        for (int ks = 0; ks < 2; ++ks) {
#pragma unroll
            for (int mf = 0; mf < 2; ++mf) {
                bf16x8 af = *(const bf16x8*)&kfTh[(w * 32 + mf * 16 + lm) * 72 + ks * 32 + lq * 8];
                bf16x8 afl = *(const bf16x8*)&kfTl[(w * 32 + mf * 16 + lm) * 72 + ks * 32 + lq * 8];
#pragma unroll
                for (int ef = 0; ef < 5; ++ef) {
                    bf16x8 bfh = *(const bf16x8*)&vTh[(ef * 16 + lm) * 72 + ks * 32 + lq * 8];
                    bf16x8 bfl = *(const bf16x8*)&vTl[(ef * 16 + lm) * 72 + ks * 32 + lq * 8];
                    acc[mf][ef] = __builtin_amdgcn_mfma_f32_16x16x32_bf16(af,  bfh, acc[mf][ef], 0, 0, 0);
                    acc[mf][ef] = __builtin_amdgcn_mfma_f32_16x16x32_bf16(afl, bfh, acc[mf][ef], 0, 0, 0);
                    acc[mf][ef] = __builtin_amdgcn_mfma_f32_16x16x32_bf16(af,  bfl, acc[mf][ef], 0, 0, 0);
                }
            }
        }
    }

    __syncthreads();
#pragma unroll
    for (int mf = 0; mf < 2; ++mf)
#pragma unroll
        for (int ef = 0; ef < 5; ++ef)
#pragma unroll
            for (int r = 0; r < 4; ++r) {
                int ml = w * 32 + mf * 16 + lq * 4 + r;
                int e  = ef * 16 + lm;
                ctxe[ml * 81 + e] = acc[mf][ef][r];
            }
    __syncthreads();
    const size_t SLICE = (size_t)(B_ * HEADS_) * EPAD * M_;
    const size_t obase = (size_t)slice * SLICE + (size_t)bh * EPAD * M_;
    for (int i = t; i < EPAD * 128; i += 256) {
        int e = i >> 7, ml = i & 127;
        ctxp[obase + (size_t)e * M_ + mh * 128 + ml] = ctxe[ml * 81 + e];
    }
}

// ======================================================================
// Reduce ctx partials over slices -> bf16 hi/lo ctxT[bh][e][m]
// ======================================================================
__global__ __launch_bounds__(256) void ctx_reduce(
    const float* __restrict__ ctxp, __bf16* __restrict__ ctxTh, __bf16* __restrict__ ctxTl)
{
    int idx = blockIdx.x * 256 + threadIdx.x;
    const size_t SLICE = (size_t)(B_ * HEADS_) * EPAD * M_;
    float s = 0.f;
#pragma unroll
    for (int k = 0; k < NSPLIT; ++k) s += ctxp[(size_t)k * SLICE + idx];
    __bf16 hh = (__bf16)s;
    ctxTh[idx] = hh;
    ctxTl[idx] = (__bf16)(s - (float)hh);
}

// ======================================================================
// out via MFMA (round-8: ctx in LDS + proj reg double-buffer). UNCHANGED.
// ======================================================================
__global__ __launch_bounds__(512, 2) void out_mfma(
    const __bf16* __restrict__ Qh, const __bf16* __restrict__ Ql,
    const __bf16* __restrict__ projH, const __bf16* __restrict__ projL,
    const __bf16* __restrict__ ctxTh, const __bf16* __restrict__ ctxTl,
    __bf16* __restrict__ attnH, __bf16* __restrict__ attnL)
{
    __shared__ alignas(16) __bf16 ctxLh[80 * 256];
    __shared__ alignas(16) __bf16 ctxLl[80 * 256];
    __shared__ alignas(16) __bf16 qfh[8][32][72];
    __shared__ alignas(16) __bf16 qfl[8][32][72];

    const int t    = threadIdx.x;
    const int lane = t & 63;
    const int w    = t >> 6;
    const int lm   = lane & 15;
    const int lq   = lane >> 4;
    const int bh   = blockIdx.y;
    const int b    = bh >> 4, h = bh & 15;
    const int nw   = blockIdx.x * 256 + w * 32;
    const size_t rowbase = (size_t)b * N_ * H_ + (size_t)h * DH_;

    const __bf16* cth = ctxTh + (size_t)bh * EPAD * M_;
    const __bf16* ctl = ctxTl + (size_t)bh * EPAD * M_;

    {
        const int r_in = lane >> 5;
        const int cp   = lane & 31;
#pragma unroll
        for (int c = 0; c < 5; ++c) {
            int idx = w * 5 + c;
            int r   = idx * 2 + r_in;
            int gc  = cp ^ (r & 7);
            const __bf16* gh = cth + (size_t)r * 256 + gc * 8;
            const __bf16* gl = ctl + (size_t)r * 256 + gc * 8;
            __builtin_amdgcn_global_load_lds(
                (const __attribute__((address_space(1))) void*)gh,
                (__attribute__((address_space(3))) void*)&ctxLh[idx * 512],
                16, 0, 0);
            __builtin_amdgcn_global_load_lds(
                (const __attribute__((address_space(1))) void*)gl,
                (__attribute__((address_space(3))) void*)&ctxLl[idx * 512],
                16, 0, 0);
        }
    }

    bf16x8 qh_[2][2], ql_[2][2];
#pragma unroll
    for (int nf = 0; nf < 2; ++nf)
#pragma unroll
        for (int ks = 0; ks < 2; ++ks) {
            size_t qa = rowbase + (size_t)(nw + nf * 16 + lm) * H_ + ks * 32 + lq * 8;
            qh_[nf][ks] = *(const bf16x8*)(Qh + qa);
            ql_[nf][ks] = *(const bf16x8*)(Ql + qa);
        }
    bf16x8 pc_h[4][2], pc_l[4][2];
#pragma unroll
    for (int mf = 0; mf < 4; ++mf)
#pragma unroll
        for (int ks = 0; ks < 2; ++ks) {
            size_t pa = (size_t)(mf * 16 + lm) * 64 + ks * 32 + lq * 8;
            pc_h[mf][ks] = *(const bf16x8*)(projH + pa);
            pc_l[mf][ks] = *(const bf16x8*)(projL + pa);
        }

    __syncthreads();

    f32x4 accO[2][5];
#pragma unroll
    for (int nf = 0; nf < 2; ++nf)
#pragma unroll
        for (int ef = 0; ef < 5; ++ef) accO[nf][ef] = (f32x4){0.f, 0.f, 0.f, 0.f};

#pragma unroll
    for (int mc = 0; mc < 4; ++mc) {
        const int m0 = mc * 64;
        f32x4 dsh[2][4];
#pragma unroll
        for (int nf = 0; nf < 2; ++nf)
#pragma unroll
            for (int mf = 0; mf < 4; ++mf) dsh[nf][mf] = (f32x4){0.f, 0.f, 0.f, 0.f};
#pragma unroll
        for (int mf = 0; mf < 4; ++mf)
#pragma unroll
            for (int ks = 0; ks < 2; ++ks)
#pragma unroll
                for (int nf = 0; nf < 2; ++nf) {
                    dsh[nf][mf] = __builtin_amdgcn_mfma_f32_16x16x32_bf16(qh_[nf][ks], pc_h[mf][ks], dsh[nf][mf], 0, 0, 0);
                    dsh[nf][mf] = __builtin_amdgcn_mfma_f32_16x16x32_bf16(ql_[nf][ks], pc_h[mf][ks], dsh[nf][mf], 0, 0, 0);
                    dsh[nf][mf] = __builtin_amdgcn_mfma_f32_16x16x32_bf16(qh_[nf][ks], pc_l[mf][ks], dsh[nf][mf], 0, 0, 0);
                }
        bf16x8 pn_h[4][2], pn_l[4][2];
        if (mc < 3) {
#pragma unroll
            for (int mf = 0; mf < 4; ++mf)
#pragma unroll
                for (int ks = 0; ks < 2; ++ks) {
                    size_t pa = (size_t)((m0 + 64) + mf * 16 + lm) * 64 + ks * 32 + lq * 8;
                    pn_h[mf][ks] = *(const bf16x8*)(projH + pa);
                    pn_l[mf][ks] = *(const bf16x8*)(projL + pa);
                }
        }
#pragma unroll
        for (int nf = 0; nf < 2; ++nf)
#pragma unroll
            for (int mf = 0; mf < 4; ++mf)
#pragma unroll
                for (int r = 0; r < 4; ++r) {
                    float qf = RATIO * (__expf(NORMALIZER * dsh[nf][mf][r]) + KEPS);
                    __bf16 hh = (__bf16)qf;
                    int nloc = nf * 16 + lq * 4 + r;
                    qfh[w][nloc][mf * 16 + lm] = hh;
                    qfl[w][nloc][mf * 16 + lm] = (__bf16)(qf - (float)hh);
                }
#pragma unroll
        for (int ks = 0; ks < 2; ++ks) {
            bf16x8 af[2], afl[2];
#pragma unroll
            for (int nf = 0; nf < 2; ++nf) {
                af[nf]  = *(const bf16x8*)&qfh[w][nf * 16 + lm][ks * 32 + lq * 8];
                afl[nf] = *(const bf16x8*)&qfl[w][nf * 16 + lm][ks * 32 + lq * 8];
            }
#pragma unroll
            for (int ef = 0; ef < 5; ++ef) {
                int row = ef * 16 + lm;
                int sc  = ((m0 >> 3) + ks * 4 + lq) ^ (lm & 7);
                int off = row * 256 + sc * 8;
                bf16x8 bfh = *(const bf16x8*)&ctxLh[off];
                bf16x8 bfl = *(const bf16x8*)&ctxLl[off];
#pragma unroll
                for (int nf = 0; nf < 2; ++nf) {
                    accO[nf][ef] = __builtin_amdgcn_mfma_f32_16x16x32_bf16(af[nf],  bfh, accO[nf][ef], 0, 0, 0);
                    accO[nf][ef] = __builtin_amdgcn_mfma_f32_16x16x32_bf16(afl[nf], bfh, accO[nf][ef], 0, 0, 0);
                    accO[nf][ef] = __builtin_amdgcn_mfma_f32_16x16x32_bf16(af[nf],  bfl, accO[nf][ef], 0, 0, 0);
                }
            }
        }
        if (mc < 3) {
#pragma unroll
            for (int mf = 0; mf < 4; ++mf)
#pragma unroll
                for (int ks = 0; ks < 2; ++ks) {
                    pc_h[mf][ks] = pn_h[mf][ks];
                    pc_l[mf][ks] = pn_l[mf][ks];
                }
        }
    }

#pragma unroll
    for (int nf = 0; nf < 2; ++nf) {
        float dinv[4];
#pragma unroll
        for (int r = 0; r < 4; ++r) {
            float den = __shfl(accO[nf][4][r], lane & 48);
            dinv[r] = 1.f / den;
        }
#pragma unroll
        for (int ef = 0; ef < 4; ++ef)
#pragma unroll
            for (int r = 0; r < 4; ++r) {
                float o = accO[nf][ef][r] * dinv[r];
                __bf16 hh = (__bf16)o;
                size_t oa = rowbase + (size_t)(nw + nf * 16 + lq * 4 + r) * H_ + ef * 16 + lm;
                attnH[oa] = hh;
                attnL[oa] = (__bf16)(o - (float)hh);
            }
    }
}

// ======================================================================
extern "C" void kernel_launch(void* const* d_in, const int* in_sizes, int n_in,
                              void* d_out, int out_size, void* d_ws, size_t ws_size,
                              hipStream_t stream) {
    const float* hs   = (const float*)d_in[0];
    const float* Wq   = (const float*)d_in[1];
    const float* bq   = (const float*)d_in[2];
    const float* Wk   = (const float*)d_in[3];
    const float* bk   = (const float*)d_in[4];
    const float* Wv   = (const float*)d_in[5];
    const float* bv   = (const float*)d_in[6];
    const float* Wo   = (const float*)d_in[7];
    const float* bo   = (const float*)d_in[8];
    const float* proj = (const float*)d_in[9];
    float* out = (float*)d_out;

    const size_t QSZ = (size_t)B_ * N_ * H_;           // 8388608
    const size_t WSZ = (size_t)H_ * H_;                // 1048576
    const size_t CTXT = (size_t)B_ * HEADS_ * EPAD * M_;  // 655360

    __bf16* Qh  = (__bf16*)d_ws;
    __bf16* Ql  = Qh + QSZ;
    __bf16* Kh  = Ql + QSZ;
    __bf16* Kl  = Kh + QSZ;
    __bf16* Vh  = Kl + QSZ;
    __bf16* Vl  = Vh + QSZ;
    __bf16* hsH = Vl + QSZ;      // aliased as attnH after hs consumed
    __bf16* hsL = hsH + QSZ;     // aliased as attnL
    __bf16* WH  = hsL + QSZ;
    __bf16* WL  = WH + 4 * WSZ;
    __bf16* projH = WL + 4 * WSZ;
    __bf16* projL = projH + (size_t)M_ * DH_;
    __bf16* ctxTh = projL + (size_t)M_ * DH_;
    __bf16* ctxTl = ctxTh + CTXT;
    float*  diag  = (float*)(ctxTl + CTXT);
    float*  parts = diag + (size_t)B_ * HEADS_ * N_;
    float*  stab  = parts + 2048;
    float*  ctxp  = stab + 16;

    __bf16 *WoH = WH + 3*WSZ, *WoL = WL + 3*WSZ;

    // 0) splits
    split_bf16<<<QSZ / 4 / 256, 256, 0, stream>>>(hs, hsH, hsL);
    split_w<<<dim3(WSZ / 4 / 256, 4), 256, 0, stream>>>(Wq, Wk, Wv, Wo, WH, WL);
    split_bf16<<<(M_ * DH_) / 4 / 256, 256, 0, stream>>>(proj, projH, projL);

    // 1) merged Q,K,V = hs @ {Wq,Wk,Wv}^T + b -> bf16 hi/lo, diag fused
    gemm_qkv<<<dim3(H_ / 128, (B_ * N_) / 128), 512, 0, stream>>>(
        hsH, hsL, WH, WL, bq, bk, bv, Qh, Ql, Kh, Kl, Vh, Vl, diag, parts);

    // 2) global stabilizer from 512 per-block maxes
    reduce_stab<<<1, 256, 0, stream>>>(parts, stab, 512);

    // 3) ctx partials (MFMA)
    ctx_mfma<<<dim3(NSPLIT, 2, B_ * HEADS_), 256, 0, stream>>>(
        Kh, Kl, Vh, Vl, projH, projL, diag, stab, ctxp);

    // 4) reduce partials -> bf16 ctxT
    ctx_reduce<<<(B_ * HEADS_ * EPAD * M_) / 256, 256, 0, stream>>>(ctxp, ctxTh, ctxTl);

    // 5) out (MFMA), 512 thr / 8 waves, ctxT staged in LDS
    out_mfma<<<dim3(N_ / 256, B_ * HEADS_), 512, 0, stream>>>(
        Qh, Ql, projH, projL, ctxTh, ctxTl, hsH, hsL);

    // 6) final projection fp32 out
    gemm_out<<<dim3(H_ / 128, (B_ * N_) / 128), 512, 0, stream>>>(
        hsH, hsL, WoH, WoL, bo, out);
}